// Round 11
// baseline (724.661 us; speedup 1.0000x reference)
//
#include <hip/hip_runtime.h>
#include <hip/hip_bf16.h>
#include <math.h>

typedef unsigned int u32;
typedef unsigned short u16;
typedef __attribute__((ext_vector_type(8))) short bf16x8;
typedef __attribute__((ext_vector_type(4))) float f32x4;

__device__ __forceinline__ float b2f(u16 u) { union { u32 i; float f; } c; c.i = ((u32)u) << 16; return c.f; }
__device__ __forceinline__ u16 f2b(float f) { __hip_bfloat16 h = __float2bfloat16(f); u16 r; __builtin_memcpy(&r, &h, 2); return r; }
__device__ __forceinline__ float b2f_lo(u32 w) { union { u32 i; float f; } c; c.i = w << 16; return c.f; }
__device__ __forceinline__ float b2f_hi(u32 w) { union { u32 i; float f; } c; c.i = w & 0xffff0000u; return c.f; }
__device__ __forceinline__ u32 pk2(float a, float b) { return (u32)f2b(a) | ((u32)f2b(b) << 16); }

__device__ __forceinline__ float wave_sum(float v) {
    #pragma unroll
    for (int off = 32; off > 0; off >>= 1) v += __shfl_xor(v, off, 64);
    return v;
}

// ---- DPP reductions (VALU pipe, not LDS pipe) ----
template<int CTRL>
__device__ __forceinline__ float dpp_addf(float v) {
    int y = __builtin_amdgcn_update_dpp(0, __builtin_bit_cast(int, v), CTRL, 0xF, 0xF, true);
    return v + __builtin_bit_cast(float, y);
}
__device__ __forceinline__ float sum16_dpp(float v) {
    v = dpp_addf<0xB1>(v);
    v = dpp_addf<0x4E>(v);
    v = dpp_addf<0x141>(v);
    v = dpp_addf<0x140>(v);
    return v;
}
__device__ __forceinline__ float sum8_dpp(float v) {
    v = dpp_addf<0xB1>(v);
    v = dpp_addf<0x4E>(v);
    v = dpp_addf<0x141>(v);
    return v;
}

// ================= bf16 MFMA GEMM (64x128 tile, 4 waves of 32x64) ============
template<bool AF32>
__global__ __launch_bounds__(256) void mfma_gemm_kernel(
    const void* __restrict__ Av, const u16* __restrict__ B,
    const float* __restrict__ bias, const float* __restrict__ rowscale,
    u16* __restrict__ Cb, int M, int N, int K,
    const void* __restrict__ Av1, const u16* __restrict__ B1,
    const float* __restrict__ bias1, u16* __restrict__ Cb1)
{
    if (blockIdx.z) { Av = Av1; B = B1; bias = bias1; Cb = Cb1; }
    __shared__ u16 lds[(64 + 128) * 64];   // A bytes [0,8192), B bytes [8192,24576)
    const int tid = threadIdx.x;
    const int wid = tid >> 6, lane = tid & 63;
    const int wr = wid >> 1, wc = wid & 1;
    const int m0 = blockIdx.y * 64, n0 = blockIdx.x * 128;

    f32x4 acc[2][4] = {};

    for (int k0 = 0; k0 < K; k0 += 64) {
        #pragma unroll
        for (int s = 0; s < 2; ++s) {
            int idx = tid + s * 256;
            int row = idx >> 3, g = idx & 7;
            int row_g = m0 + row; if (row_g >= M) row_g = M - 1;
            int swz = ((g << 4) ^ ((row & 7) << 4));
            if (AF32) {
                const float* src = (const float*)Av + (size_t)row_g * K + k0 + g * 8;
                float4 v0 = *(const float4*)src;
                float4 v1 = *(const float4*)(src + 4);
                uint4 pk;
                pk.x = pk2(v0.x, v0.y); pk.y = pk2(v0.z, v0.w);
                pk.z = pk2(v1.x, v1.y); pk.w = pk2(v1.z, v1.w);
                *(uint4*)((char*)lds + row * 128 + swz) = pk;
            } else {
                f32x4 v = *(const f32x4*)((const u16*)Av + (size_t)row_g * K + k0 + g * 8);
                *(f32x4*)((char*)lds + row * 128 + swz) = v;
            }
        }
        #pragma unroll
        for (int s = 0; s < 4; ++s) {
            int idx = tid + s * 256;
            int row = idx >> 3, g = idx & 7;
            int row_g = n0 + row; if (row_g >= N) row_g = N - 1;
            f32x4 v = *(const f32x4*)(B + (size_t)row_g * K + k0 + g * 8);
            *(f32x4*)((char*)lds + 8192 + row * 128 + ((g << 4) ^ ((row & 7) << 4))) = v;
        }
        __syncthreads();
        #pragma unroll
        for (int ks = 0; ks < 2; ++ks) {
            const int off = (ks * 64 + ((lane >> 4) << 4)) ^ ((lane & 7) << 4);
            const int ra = lane & 15;
            bf16x8 af[2], bfr[4];
            #pragma unroll
            for (int i = 0; i < 2; ++i)
                af[i] = *(bf16x8*)((char*)lds + (wr * 32 + i * 16 + ra) * 128 + off);
            #pragma unroll
            for (int j = 0; j < 4; ++j)
                bfr[j] = *(bf16x8*)((char*)lds + 8192 + (wc * 64 + j * 16 + ra) * 128 + off);
            #pragma unroll
            for (int i = 0; i < 2; ++i)
                #pragma unroll
                for (int j = 0; j < 4; ++j)
                    acc[i][j] = __builtin_amdgcn_mfma_f32_16x16x32_bf16(af[i], bfr[j], acc[i][j], 0, 0, 0);
        }
        __syncthreads();
    }

    const int cr = lane >> 4, ccol = lane & 15;
    #pragma unroll
    for (int i = 0; i < 2; ++i) {
        #pragma unroll
        for (int j = 0; j < 4; ++j) {
            int colg = n0 + wc * 64 + j * 16 + ccol;
            if (colg >= N) continue;
            float badd = bias ? bias[colg] : 0.f;
            #pragma unroll
            for (int reg = 0; reg < 4; ++reg) {
                int rowg = m0 + wr * 32 + i * 16 + cr * 4 + reg;
                if (rowg >= M) continue;
                float v = acc[i][j][reg] + badd;
                if (rowscale) v *= rowscale[rowg];
                Cb[(size_t)rowg * N + colg] = f2b(v);
            }
        }
    }
}

// ================= mega-fused 4-layer graph transformer ======================
// Block = 1 sequence (64 rows), 512 threads / 8 waves, both types in one grid.
// 4 barriers/layer. Pack-write swizzle folds c (conflict-free octets);
// wfT2 first-16 prefetched to regs; u-phase float4 ctx reads.
__global__ __launch_bounds__(512, 4) void fused_transformer_kernel(
    const float* __restrict__ gh, const int* __restrict__ dg_seqs,
    const int* __restrict__ pt_seqs,
    const u16* __restrict__ wrN,   // [8][16 gn][8 kc][64 lane][8] bf16
    const u32* __restrict__ wfT2,  // [8][128 d2][256 n] packed bf16 pairs
    const float* __restrict__ ar,  // [8][128]
    const float* __restrict__ lng, const float* __restrict__ lnb,  // [8][256]
    float* __restrict__ embT)      // [2048,256]
{
    __shared__ u16 ldsA[64 * 256];       // 32KB: [c:4][row:64][128B swizzled]
    __shared__ float scoreH[2][64];      // per-head accumulated scores
    __shared__ float ctxS[256];
    __shared__ float uS[2][256];

    const int tid = threadIdx.x;
    const int bx = blockIdx.x;
    const int t = bx >> 10, s = bx & 1023;
    const int r = tid >> 3, o8 = tid & 7;        // row 0..63, col-octant 0..7
    const int wid = tid >> 6, lane = tid & 63;
    const int hd = wid >> 2;                     // head (waves 0-3 / 4-7)
    const int g4 = lane >> 4, cl = lane & 15;

    const int* seqs = t ? pt_seqs : dg_seqs;
    const int un = tid & 255, uhalf = tid >> 8;  // u-matvec assignment

    // ---- gather h0 (thread's 32 cols of its row) ----
    float4 y[8];
    {
        int node = seqs[s * 64 + r];
        const float* src = gh + (size_t)node * 256 + o8 * 32;
        #pragma unroll
        for (int v = 0; v < 8; ++v) y[v] = *(const float4*)(src + v * 4);
    }

    for (int l = 0; l < 4; ++l) {
        const int li = t * 4 + l;
        const u32* wp = wfT2 + (size_t)li * 32768 + (size_t)uhalf * 16384 + un;

        // ---- prefetch first 16 wfT2 words (data-independent addresses) ----
        u32 wpre[16];
        #pragma unroll
        for (int i = 0; i < 16; ++i) wpre[i] = wp[(size_t)i * 256];

        // ---- pack y -> swizzled bf16 A-LDS (c folded into XOR); zero scoreH --
        {
            const int c = o8 >> 1, gb = (o8 & 1) * 4;
            #pragma unroll
            for (int gg = 0; gg < 4; ++gg) {
                float4 a = y[2 * gg], b = y[2 * gg + 1];
                uint4 pk;
                pk.x = pk2(a.x, a.y); pk.y = pk2(a.z, a.w);
                pk.z = pk2(b.x, b.y); pk.w = pk2(b.z, b.w);
                int g = gb + gg;
                int off = ((g << 4) ^ ((r & 7) << 4)) ^ (c << 4);
                *(uint4*)((char*)ldsA + c * 8192 + r * 128 + off) = pk;
            }
            if (tid < 128) ((float*)scoreH)[tid] = 0.f;
        }
        __syncthreads();   // B1

        // ---- fr = h @ wr^T : wave wid -> cols wid*32..+31, rows 0..63 ----
        f32x4 acc[4][2] = {};
        {
            const u16* wrl = wrN + (size_t)li * 65536;
            const int ra = lane & 15;
            #pragma unroll
            for (int kc = 0; kc < 8; ++kc) {
                const int c = kc >> 1, ks = kc & 1;
                const int off = ((ks * 64 + ((lane >> 4) << 4)) ^ ((lane & 7) << 4)) ^ (c << 4);
                bf16x8 af[4], bfr[2];
                #pragma unroll
                for (int i = 0; i < 4; ++i)
                    af[i] = *(bf16x8*)((char*)ldsA + c * 8192 + (i * 16 + ra) * 128 + off);
                #pragma unroll
                for (int j = 0; j < 2; ++j)
                    bfr[j] = *(const bf16x8*)(wrl + ((size_t)((wid * 2 + j) * 8 + kc) << 9) + lane * 8);
                #pragma unroll
                for (int i = 0; i < 4; ++i)
                    #pragma unroll
                    for (int j = 0; j < 2; ++j)
                        acc[i][j] = __builtin_amdgcn_mfma_f32_16x16x32_bf16(af[i], bfr[j], acc[i][j], 0, 0, 0);
            }
        }

        // ---- scores over this wave's 32 cols -> DPP reduce -> atomicAdd ----
        {
            const float* arl = ar + li * 128;
            float arj[2];
            #pragma unroll
            for (int j = 0; j < 2; ++j) arj[j] = arl[(wid & 3) * 32 + j * 16 + cl];
            #pragma unroll
            for (int i = 0; i < 4; ++i)
                #pragma unroll
                for (int reg = 0; reg < 4; ++reg) {
                    float sc;
                    {
                        float x0 = acc[i][0][reg], x1 = acc[i][1][reg];
                        sc = (x0 >= 0.f ? x0 : 0.01f * x0) * arj[0]
                           + (x1 >= 0.f ? x1 : 0.01f * x1) * arj[1];
                    }
                    sc = sum16_dpp(sc);
                    if (cl == 0) atomicAdd(&scoreH[hd][i * 16 + g4 * 4 + reg], sc);
                }
        }
        __syncthreads();   // B2

        // ---- softmax in-register: lane's 16 rows depend only on g4 ----
        float p[4][4];
        {
            const float* sc = scoreH[hd];
            #pragma unroll
            for (int i = 0; i < 4; ++i)
                *(float4*)p[i] = *(const float4*)(sc + i * 16 + g4 * 4);
            float mx = -1e30f;
            #pragma unroll
            for (int i = 0; i < 4; ++i)
                #pragma unroll
                for (int reg = 0; reg < 4; ++reg) mx = fmaxf(mx, p[i][reg]);
            mx = fmaxf(mx, __shfl_xor(mx, 16, 64));
            mx = fmaxf(mx, __shfl_xor(mx, 32, 64));
            float sme = 0.f;
            #pragma unroll
            for (int i = 0; i < 4; ++i)
                #pragma unroll
                for (int reg = 0; reg < 4; ++reg) {
                    p[i][reg] = __expf(p[i][reg] - mx);
                    sme += p[i][reg];
                }
            sme += __shfl_xor(sme, 16, 64);
            sme += __shfl_xor(sme, 32, 64);
            float inv = 1.f / sme;
            #pragma unroll
            for (int i = 0; i < 4; ++i)
                #pragma unroll
                for (int reg = 0; reg < 4; ++reg) p[i][reg] *= inv;
        }

        // ---- ctx over wave's 32 cols ----
        {
            #pragma unroll
            for (int j = 0; j < 2; ++j) {
                float c = 0.f;
                #pragma unroll
                for (int i = 0; i < 4; ++i)
                    #pragma unroll
                    for (int reg = 0; reg < 4; ++reg)
                        c = fmaf(p[i][reg], acc[i][j][reg], c);
                c += __shfl_xor(c, 16, 64);
                c += __shfl_xor(c, 32, 64);
                if (g4 == 0) ctxS[wid * 32 + j * 16 + cl] = c;
            }
        }
        __syncthreads();   // B3

        // ---- u[n] = sum_d ctx[d]*wf[n][d]; prefetched head, float4 ctx reads --
        {
            const float* cx = ctxS + uhalf * 128;
            float ua0 = 0.f, ua1 = 0.f, ua2 = 0.f, ua3 = 0.f;
            #pragma unroll
            for (int d2 = 0; d2 < 64; d2 += 4) {
                u32 w0, w1, w2, w3;
                if (d2 < 16) {
                    w0 = wpre[d2]; w1 = wpre[d2 + 1]; w2 = wpre[d2 + 2]; w3 = wpre[d2 + 3];
                } else {
                    w0 = wp[(size_t)(d2 + 0) * 256];
                    w1 = wp[(size_t)(d2 + 1) * 256];
                    w2 = wp[(size_t)(d2 + 2) * 256];
                    w3 = wp[(size_t)(d2 + 3) * 256];
                }
                float4 c0 = *(const float4*)(cx + 2 * d2);
                float4 c1 = *(const float4*)(cx + 2 * d2 + 4);
                ua0 = fmaf(c0.x, b2f_lo(w0), ua0);
                ua0 = fmaf(c0.y, b2f_hi(w0), ua0);
                ua1 = fmaf(c0.z, b2f_lo(w1), ua1);
                ua1 = fmaf(c0.w, b2f_hi(w1), ua1);
                ua2 = fmaf(c1.x, b2f_lo(w2), ua2);
                ua2 = fmaf(c1.y, b2f_hi(w2), ua2);
                ua3 = fmaf(c1.z, b2f_lo(w3), ua3);
                ua3 = fmaf(c1.w, b2f_hi(w3), ua3);
            }
            uS[uhalf][un] = (ua0 + ua1) + (ua2 + ua3);
        }
        __syncthreads();   // B4

        // ---- h = LN(h + u) (8 threads per row; DPP sum over 8 lanes) ----
        {
            #pragma unroll
            for (int v = 0; v < 8; ++v) {
                int c0 = o8 * 32 + v * 4;
                float4 u0 = *(const float4*)&uS[0][c0];
                float4 u1 = *(const float4*)&uS[1][c0];
                y[v].x += u0.x + u1.x; y[v].y += u0.y + u1.y;
                y[v].z += u0.z + u1.z; y[v].w += u0.w + u1.w;
            }
            float sm = 0.f, qq = 0.f;
            #pragma unroll
            for (int v = 0; v < 8; ++v) {
                sm += y[v].x + y[v].y + y[v].z + y[v].w;
                qq += y[v].x * y[v].x + y[v].y * y[v].y + y[v].z * y[v].z + y[v].w * y[v].w;
            }
            sm = sum8_dpp(sm);
            qq = sum8_dpp(qq);
            float mean = sm * (1.f / 256.f);
            float var = qq * (1.f / 256.f) - mean * mean;
            float inv = rsqrtf(var + 1e-5f);
            const float* gl = lng + li * 256 + o8 * 32;
            const float* bl = lnb + li * 256 + o8 * 32;
            if (l < 3) {
                #pragma unroll
                for (int v = 0; v < 8; ++v) {
                    float4 gv = *(const float4*)(gl + v * 4);
                    float4 bv = *(const float4*)(bl + v * 4);
                    y[v].x = (y[v].x - mean) * inv * gv.x + bv.x;
                    y[v].y = (y[v].y - mean) * inv * gv.y + bv.y;
                    y[v].z = (y[v].z - mean) * inv * gv.z + bv.z;
                    y[v].w = (y[v].w - mean) * inv * gv.w + bv.w;
                }
            } else if (r == 0) {
                float* dst = embT + (size_t)(t * 1024 + s) * 256 + o8 * 32;
                #pragma unroll
                for (int v = 0; v < 8; ++v) {
                    float4 gv = *(const float4*)(gl + v * 4);
                    float4 bv = *(const float4*)(bl + v * 4);
                    float4 o;
                    o.x = (y[v].x - mean) * inv * gv.x + bv.x;
                    o.y = (y[v].y - mean) * inv * gv.y + bv.y;
                    o.z = (y[v].z - mean) * inv * gv.z + bv.z;
                    o.w = (y[v].w - mean) * inv * gv.w + bv.w;
                    *(float4*)(dst + v * 4) = o;
                }
            }
        }
        // no end barrier: ordering provided by B2..B4 (round-8 analysis)
    }
}

// ================= fp32 tiled GEMM (small M), dual-set via blockIdx.z ========
template<bool BT>
__global__ __launch_bounds__(256) void gemm_kernel(
    const float* __restrict__ A, const float* __restrict__ B,
    const float* __restrict__ bias, const float* __restrict__ rowscale,
    float* __restrict__ C,
    int M, int N, int K, int lda, int ldb, int ldc, int coff, int act,
    const float* __restrict__ A1, const float* __restrict__ B1,
    const float* __restrict__ bias1, float* __restrict__ C1, int coff1)
{
    if (blockIdx.z) { A = A1; B = B1; bias = bias1; C = C1; coff = coff1; }
    __shared__ float As[32][64 + 4];
    __shared__ float Bs[32][64 + 4];
    const int tid = threadIdx.x;
    const int m0 = blockIdx.y * 64;
    const int n0 = blockIdx.x * 64;
    const int ty = tid >> 4, tx = tid & 15;
    float acc[4][4] = {};
    for (int k0 = 0; k0 < K; k0 += 32) {
        #pragma unroll
        for (int r = 0; r < 2; ++r) {
            int f4 = tid + r * 256;
            int arw = f4 >> 3, af = (f4 & 7) << 2;
            float4 v = make_float4(0.f, 0.f, 0.f, 0.f);
            int grow = m0 + arw;
            if (grow < M) {
                v = *(const float4*)(A + (size_t)grow * lda + k0 + af);
                if (rowscale) { float s = rowscale[grow]; v.x *= s; v.y *= s; v.z *= s; v.w *= s; }
            }
            As[af + 0][arw] = v.x; As[af + 1][arw] = v.y; As[af + 2][arw] = v.z; As[af + 3][arw] = v.w;
        }
        #pragma unroll
        for (int r = 0; r < 2; ++r) {
            int f4 = tid + r * 256;
            int col = f4 >> 3, kf = (f4 & 7) << 2;
            float4 v = make_float4(0.f, 0.f, 0.f, 0.f);
            if (n0 + col < N) v = *(const float4*)(B + (size_t)(n0 + col) * ldb + k0 + kf);
            Bs[kf + 0][col] = v.x; Bs[kf + 1][col] = v.y; Bs[kf + 2][col] = v.z; Bs[kf + 3][col] = v.w;
        }
        __syncthreads();
        #pragma unroll
        for (int kk = 0; kk < 32; ++kk) {
            float4 a4 = *(const float4*)&As[kk][ty << 2];
            float4 b4 = *(const float4*)&Bs[kk][tx << 2];
            float a[4] = {a4.x, a4.y, a4.z, a4.w};
            float b[4] = {b4.x, b4.y, b4.z, b4.w};
            #pragma unroll
            for (int i = 0; i < 4; ++i)
                #pragma unroll
                for (int j = 0; j < 4; ++j)
                    acc[i][j] = fmaf(a[i], b[j], acc[i][j]);
        }
        __syncthreads();
    }
    #pragma unroll
    for (int i = 0; i < 4; ++i) {
        int row = m0 + (ty << 2) + i;
        if (row >= M) continue;
        #pragma unroll
        for (int j = 0; j < 4; ++j) {
            int col = n0 + (tx << 2) + j;
            if (col >= N) continue;
            float v = acc[i][j];
            if (bias) v += bias[col];
            if (act == 1) v = fmaxf(v, 0.f);
            else if (act == 2) v = (v > 0.f) ? v : expm1f(v);
            C[(size_t)row * ldc + coff + col] = v;
        }
    }
}

// ================= merged converts (one dispatch, 2048 blocks) ===============
__global__ __launch_bounds__(256) void conv_all_kernel(
    const float* __restrict__ fc_w0, const float* __restrict__ fc_w1,
    const float* __restrict__ gcn_w, const float* __restrict__ gt_wr,
    const float* __restrict__ gt_wf,
    u16* __restrict__ fcw_b, u16* __restrict__ gcnw_b,
    u16* __restrict__ wrN, u32* __restrict__ wfT2)
{
    int bid = blockIdx.x, tid = threadIdx.x;
    if (bid < 256) {
        // fc_w0 / fc_w1 flat bf16 convert
        const float* src = bid < 128 ? fc_w0 : fc_w1;
        u16* dst = fcw_b + (bid < 128 ? 0 : 131072);
        int i = ((bid & 127) * 256 + tid) * 4;
        float4 v = *(const float4*)(src + i);
        *(uint2*)(dst + i) = make_uint2(pk2(v.x, v.y), pk2(v.z, v.w));
    } else if (bid < 768) {
        // gcn_w [2][256][256] -> transposed bf16
        int idx = (bid - 256) * 256 + tid;   // 0..131071
        int l = idx >> 16, rem = idx & 65535;
        int k = rem >> 8, n = rem & 255;
        gcnw_b[(size_t)l * 65536 + n * 256 + k] = f2b(gcn_w[(size_t)l * 65536 + k * 256 + n]);
    } else if (bid < 1024) {
        // gt_wr -> frag-major wrN
        int idx = (bid - 768) * 256 + tid;   // 0..65535
        int lane = idx & 63;
        int kc = (idx >> 6) & 7;
        int gn = (idx >> 9) & 15;
        int l = idx >> 13;
        int row = gn * 16 + (lane & 15);
        int k0 = kc * 32 + (lane >> 4) * 8;
        const float* src = gt_wr + ((size_t)l * 256 + row) * 256 + k0;
        float4 v0 = *(const float4*)src;
        float4 v1 = *(const float4*)(src + 4);
        uint4 pk;
        pk.x = pk2(v0.x, v0.y); pk.y = pk2(v0.z, v0.w);
        pk.z = pk2(v1.x, v1.y); pk.w = pk2(v1.z, v1.w);
        *(uint4*)(wrN + (size_t)idx * 8) = pk;
    } else {
        // gt_wf -> wfT2 [8][128 d2][256 n]
        int idx = (bid - 1024) * 256 + tid;  // 0..262143
        int n = idx & 255;
        int d2 = (idx >> 8) & 127;
        int l = idx >> 15;
        const float* src = gt_wf + ((size_t)l * 256 + n) * 256 + 2 * d2;
        wfT2[idx] = pk2(src[0], src[1]);
    }
}

// ================= CSR build (4 edges/thread, pipelined atomics) =============
#define EDGE_CAP 128
__global__ __launch_bounds__(256) void bucket_fill_kernel(
    const int* __restrict__ src, const int* __restrict__ dst,
    int* __restrict__ ebuf, int* __restrict__ cursor, int* __restrict__ cnt_out, int ne)
{
    int e0 = (blockIdx.x * 256 + threadIdx.x) * 4;
    if (e0 >= ne) return;
    int4 s4 = *(const int4*)(src + e0);
    int4 d4 = *(const int4*)(dst + e0);
    atomicAdd(&cnt_out[s4.x], 1);
    atomicAdd(&cnt_out[s4.y], 1);
    atomicAdd(&cnt_out[s4.z], 1);
    atomicAdd(&cnt_out[s4.w], 1);
    int p0 = atomicAdd(&cursor[d4.x], 1);
    int p1 = atomicAdd(&cursor[d4.y], 1);
    int p2 = atomicAdd(&cursor[d4.z], 1);
    int p3 = atomicAdd(&cursor[d4.w], 1);
    if (p0 < EDGE_CAP) ebuf[(size_t)d4.x * EDGE_CAP + p0] = s4.x;
    if (p1 < EDGE_CAP) ebuf[(size_t)d4.y * EDGE_CAP + p1] = s4.y;
    if (p2 < EDGE_CAP) ebuf[(size_t)d4.z * EDGE_CAP + p2] = s4.z;
    if (p3 < EDGE_CAP) ebuf[(size_t)d4.w * EDGE_CAP + p3] = s4.w;
}
__global__ __launch_bounds__(256) void deg_fin_kernel(const int* __restrict__ cnt, float* __restrict__ dinv, int n) {
    int i = blockIdx.x * 256 + threadIdx.x;
    if (i < n) dinv[i] = rsqrtf(fmaxf((float)cnt[i], 1.0f));
}

// ================= CSR aggregate, skips dead outputs per layer ===============
template<bool WF, bool WB>
__global__ __launch_bounds__(256) void csr_agg_kernel(
    const u16* __restrict__ x, const int* __restrict__ ebuf,
    const int* __restrict__ deg, float* __restrict__ outf, u16* __restrict__ outb, int nnodes)
{
    int n = blockIdx.x * 4 + (threadIdx.x >> 6);
    if (n >= nnodes) return;
    int lane = threadIdx.x & 63;
    int d = deg[n];
    float dinv = rsqrtf(fmaxf((float)d, 1.0f));
    if (d > EDGE_CAP) d = EDGE_CAP;
    const int* eb = ebuf + (size_t)n * EDGE_CAP;
    const int co = lane << 2;
    float a0 = 0.f, a1 = 0.f, a2 = 0.f, a3 = 0.f;
    int k = 0;
    for (; k + 4 <= d; k += 4) {
        int4 s4 = *(const int4*)(eb + k);
        uint2 va = *(const uint2*)(x + (size_t)s4.x * 256 + co);
        uint2 vb = *(const uint2*)(x + (size_t)s4.y * 256 + co);
        uint2 vc = *(const uint2*)(x + (size_t)s4.z * 256 + co);
        uint2 vd = *(const uint2*)(x + (size_t)s4.w * 256 + co);
        a0 += b2f_lo(va.x) + b2f_lo(vb.x) + b2f_lo(vc.x) + b2f_lo(vd.x);
        a1 += b2f_hi(va.x) + b2f_hi(vb.x) + b2f_hi(vc.x) + b2f_hi(vd.x);
        a2 += b2f_lo(va.y) + b2f_lo(vb.y) + b2f_lo(vc.y) + b2f_lo(vd.y);
        a3 += b2f_hi(va.y) + b2f_hi(vb.y) + b2f_hi(vc.y) + b2f_hi(vd.y);
    }
    for (; k < d; ++k) {
        int s = eb[k];
        uint2 v = *(const uint2*)(x + (size_t)s * 256 + co);
        a0 += b2f_lo(v.x); a1 += b2f_hi(v.x);
        a2 += b2f_lo(v.y); a3 += b2f_hi(v.y);
    }
    a0 = fmaxf(a0 * dinv, 0.f); a1 = fmaxf(a1 * dinv, 0.f);
    a2 = fmaxf(a2 * dinv, 0.f); a3 = fmaxf(a3 * dinv, 0.f);
    if (WF) *(float4*)(outf + (size_t)n * 256 + co) = make_float4(a0, a1, a2, a3);
    if (WB) *(uint2*)(outb + (size_t)n * 256 + co) = make_uint2(pk2(a0, a1), pk2(a2, a3));
}

// ================= fused MLP tail: m2 = relu(m1@w2^T+b2); out = sigmoid(m2.w3+b3)
__global__ __launch_bounds__(256) void mlp_tail_kernel(
    const float* __restrict__ m1, const float* __restrict__ w2,
    const float* __restrict__ b2, const float* __restrict__ w3,
    const float* __restrict__ b3, float* __restrict__ out)
{
    __shared__ float rowS[4][256];
    const int w = threadIdx.x >> 6, lane = threadIdx.x & 63;
    const int row = blockIdx.x * 4 + w;
    *(float4*)&rowS[w][lane * 4] = *(const float4*)(m1 + (size_t)row * 256 + lane * 4);
    __syncthreads();
    const float* rp = rowS[w];
    float v0 = b2[lane], v1 = b2[64 + lane];
    const float* wa = w2 + (size_t)lane * 256;
    const float* wb = w2 + (size_t)(64 + lane) * 256;
    #pragma unroll 8
    for (int d = 0; d < 256; d += 4) {
        float4 rv = *(const float4*)(rp + d);
        float4 a = *(const float4*)(wa + d);
        float4 b = *(const float4*)(wb + d);
        v0 = fmaf(rv.x, a.x, v0); v0 = fmaf(rv.y, a.y, v0);
        v0 = fmaf(rv.z, a.z, v0); v0 = fmaf(rv.w, a.w, v0);
        v1 = fmaf(rv.x, b.x, v1); v1 = fmaf(rv.y, b.y, v1);
        v1 = fmaf(rv.z, b.z, v1); v1 = fmaf(rv.w, b.w, v1);
    }
    v0 = fmaxf(v0, 0.f); v1 = fmaxf(v1, 0.f);
    float s = v0 * w3[lane] + v1 * w3[64 + lane];
    s = wave_sum(s);
    if (lane == 0) out[row] = 1.f / (1.f + expf(-(s + b3[0])));
}

static inline int cdiv(int a, int b) { return (a + b - 1) / b; }

extern "C" void kernel_launch(void* const* d_in, const int* in_sizes, int n_in,
                              void* d_out, int out_size, void* d_ws, size_t ws_size,
                              hipStream_t stream)
{
    const float* feat0   = (const float*)d_in[0];
    const float* feat1   = (const float*)d_in[1];
    const float* fc_w0   = (const float*)d_in[2];
    const float* fc_b0   = (const float*)d_in[3];
    const float* fc_w1   = (const float*)d_in[4];
    const float* fc_b1   = (const float*)d_in[5];
    const float* gcn_w   = (const float*)d_in[6];
    const int*   edge_src= (const int*)d_in[7];
    const int*   edge_dst= (const int*)d_in[8];
    const int*   dg_seqs = (const int*)d_in[9];
    const int*   pt_seqs = (const int*)d_in[10];
    // 11 type_emb, 12 node_type: dead; 13 gt_wl, 15 gt_al: dead (softmax cancellation)
    const float* gt_wr   = (const float*)d_in[14];
    const float* gt_ar   = (const float*)d_in[16];
    const float* gt_wf   = (const float*)d_in[17];
    const float* ln_g    = (const float*)d_in[18];
    const float* ln_b    = (const float*)d_in[19];
    const float* proj_d_w= (const float*)d_in[20];
    const float* proj_d_b= (const float*)d_in[21];
    const float* proj_p_w= (const float*)d_in[22];
    const float* proj_p_b= (const float*)d_in[23];
    const float* ml_w1   = (const float*)d_in[24];
    const float* ml_b1   = (const float*)d_in[25];
    const float* ml_w2   = (const float*)d_in[26];
    const float* ml_b2   = (const float*)d_in[27];
    const float* ml_w3   = (const float*)d_in[28];
    const float* ml_b3   = (const float*)d_in[29];
    float* out = (float*)d_out;

    // ---- workspace layout (f32 units) ----
    float* base  = (float*)d_ws;
    float* gh    = base;                      // 10,240,000
    float* gcnR  = gh + 10240000;             // GCN-phase region (15,440,000)
    float* dego  = gcnR + 15440000;           // 40,000
    float* embT  = dego + 40000;              // 524,288 (both types)
    float* t1    = embT + 524288;             // 524,288 (both types)
    float* mx    = t1 + 524288;               // 524,288
    float* m1    = mx + 524288;               // 262,144
    float* m2    = m1 + 262144;               // 131,072 (unused now, kept for layout)
    float* wreg  = m2 + 131072;               // converted weights

    u16* tmp_b   = (u16*)gcnR;                        // 10,240,000 bf16
    int* ebuf    = (int*)(gcnR + 5120000);            // 5,120,000 int
    int* cursor  = ebuf + (size_t)40000 * EDGE_CAP;   // 40,000
    int* cnt_out = cursor + 40000;                    // 40,000
    u16* gh_b    = (u16*)(gcnR + 10320000);           // 10,240,000 bf16

    u16* fcw_b   = (u16*)wreg;                // 262,144 u16
    u16* gcnw_b  = fcw_b + 262144;            // 131,072 u16
    u16* wrN     = gcnw_b + 131072;           // 524,288 u16 (8 layers x 65,536)
    u32* wfT2    = (u32*)(wrN + 524288);      // 262,144 u32 (8 layers x 32,768)

    // ---- merged weight converts (single dispatch) ----
    conv_all_kernel<<<2048, 256, 0, stream>>>(
        fc_w0, fc_w1, gcn_w, gt_wr, gt_wf, fcw_b, gcnw_b, wrN, wfT2);

    // ---- FC projections (merged dual GEMM via blockIdx.z) -> gh_b ----
    mfma_gemm_kernel<true><<<dim3(2, cdiv(20000, 64), 2), 256, 0, stream>>>(
        feat0, fcw_b, fc_b0, nullptr, gh_b, 20000, 256, 512,
        feat1, fcw_b + 131072, fc_b1, gh_b + (size_t)20000 * 256);

    // ---- CSR build (once) ----
    hipMemsetAsync(cursor, 0, 80000 * sizeof(int), stream);
    bucket_fill_kernel<<<625, 256, 0, stream>>>(edge_src, edge_dst, ebuf, cursor, cnt_out, 640000);
    deg_fin_kernel<<<cdiv(40000, 256), 256, 0, stream>>>(cnt_out, dego, 40000);

    // ---- 2x GCN (layer 0 writes bf16 only; layer 1 writes f32 only) ----
    mfma_gemm_kernel<false><<<dim3(2, cdiv(40000, 64), 1), 256, 0, stream>>>(
        gh_b, gcnw_b, nullptr, dego, tmp_b, 40000, 256, 256,
        gh_b, gcnw_b, nullptr, tmp_b);
    csr_agg_kernel<false, true><<<10000, 256, 0, stream>>>(tmp_b, ebuf, cursor, gh, gh_b, 40000);
    mfma_gemm_kernel<false><<<dim3(2, cdiv(40000, 64), 1), 256, 0, stream>>>(
        gh_b, gcnw_b + 65536, nullptr, dego, tmp_b, 40000, 256, 256,
        gh_b, gcnw_b, nullptr, tmp_b);
    csr_agg_kernel<true, false><<<10000, 256, 0, stream>>>(tmp_b, ebuf, cursor, gh, gh_b, 40000);

    // ---- mega-fused graph transformer, both types in one dispatch ----
    fused_transformer_kernel<<<2048, 512, 0, stream>>>(
        gh, dg_seqs, pt_seqs, wrN, wfT2, gt_ar, ln_g, ln_b, embT);

    // ---- proj heads (both types per dispatch via blockIdx.z) ----
    gemm_kernel<true><<<dim3(4, 16, 2), 256, 0, stream>>>(
        embT, proj_d_w, proj_d_b, nullptr, t1, 1024, 256, 256, 256, 256, 256, 0, 2,
        embT + 262144, proj_p_w, proj_p_b, t1 + 262144, 0);
    gemm_kernel<true><<<dim3(4, 16, 2), 256, 0, stream>>>(
        t1, proj_d_w + 65536, proj_d_b + 256, nullptr, mx, 1024, 256, 256, 256, 256, 512, 0, 0,
        t1 + 262144, proj_p_w + 65536, proj_p_b + 256, mx, 256);

    // ---- predict MLP: first GEMM, then fused tail ----
    gemm_kernel<true><<<dim3(4, 16, 1), 256, 0, stream>>>(
        mx, ml_w1, ml_b1, nullptr, m1, 1024, 256, 512, 512, 512, 256, 0, 1,
        mx, ml_w1, ml_b1, m1, 0);
    mlp_tail_kernel<<<256, 256, 0, stream>>>(m1, ml_w2, ml_b2, ml_w3, ml_b3, out);
}

// Round 12
// 637.418 us; speedup vs baseline: 1.1369x; 1.1369x over previous
//
#include <hip/hip_runtime.h>
#include <hip/hip_bf16.h>
#include <math.h>

typedef unsigned int u32;
typedef unsigned short u16;
typedef __attribute__((ext_vector_type(8))) short bf16x8;
typedef __attribute__((ext_vector_type(4))) float f32x4;

__device__ __forceinline__ float b2f(u16 u) { union { u32 i; float f; } c; c.i = ((u32)u) << 16; return c.f; }
__device__ __forceinline__ u16 f2b(float f) { __hip_bfloat16 h = __float2bfloat16(f); u16 r; __builtin_memcpy(&r, &h, 2); return r; }
__device__ __forceinline__ float b2f_lo(u32 w) { union { u32 i; float f; } c; c.i = w << 16; return c.f; }
__device__ __forceinline__ float b2f_hi(u32 w) { union { u32 i; float f; } c; c.i = w & 0xffff0000u; return c.f; }
__device__ __forceinline__ u32 pk2(float a, float b) { return (u32)f2b(a) | ((u32)f2b(b) << 16); }

__device__ __forceinline__ float wave_sum(float v) {
    #pragma unroll
    for (int off = 32; off > 0; off >>= 1) v += __shfl_xor(v, off, 64);
    return v;
}

// ---- DPP reductions (VALU pipe, not LDS pipe) ----
template<int CTRL>
__device__ __forceinline__ float dpp_addf(float v) {
    int y = __builtin_amdgcn_update_dpp(0, __builtin_bit_cast(int, v), CTRL, 0xF, 0xF, true);
    return v + __builtin_bit_cast(float, y);
}
__device__ __forceinline__ float sum16_dpp(float v) {
    v = dpp_addf<0xB1>(v);
    v = dpp_addf<0x4E>(v);
    v = dpp_addf<0x141>(v);
    v = dpp_addf<0x140>(v);
    return v;
}
__device__ __forceinline__ float sum8_dpp(float v) {
    v = dpp_addf<0xB1>(v);
    v = dpp_addf<0x4E>(v);
    v = dpp_addf<0x141>(v);
    return v;
}

// ================= bf16 MFMA GEMM (64x128 tile, 4 waves of 32x64) ============
template<bool AF32>
__global__ __launch_bounds__(256) void mfma_gemm_kernel(
    const void* __restrict__ Av, const u16* __restrict__ B,
    const float* __restrict__ bias, const float* __restrict__ rowscale,
    u16* __restrict__ Cb, int M, int N, int K,
    const void* __restrict__ Av1, const u16* __restrict__ B1,
    const float* __restrict__ bias1, u16* __restrict__ Cb1)
{
    if (blockIdx.z) { Av = Av1; B = B1; bias = bias1; Cb = Cb1; }
    __shared__ u16 lds[(64 + 128) * 64];   // A bytes [0,8192), B bytes [8192,24576)
    const int tid = threadIdx.x;
    const int wid = tid >> 6, lane = tid & 63;
    const int wr = wid >> 1, wc = wid & 1;
    const int m0 = blockIdx.y * 64, n0 = blockIdx.x * 128;

    f32x4 acc[2][4] = {};

    for (int k0 = 0; k0 < K; k0 += 64) {
        #pragma unroll
        for (int s = 0; s < 2; ++s) {
            int idx = tid + s * 256;
            int row = idx >> 3, g = idx & 7;
            int row_g = m0 + row; if (row_g >= M) row_g = M - 1;
            int swz = ((g << 4) ^ ((row & 7) << 4));
            if (AF32) {
                const float* src = (const float*)Av + (size_t)row_g * K + k0 + g * 8;
                float4 v0 = *(const float4*)src;
                float4 v1 = *(const float4*)(src + 4);
                uint4 pk;
                pk.x = pk2(v0.x, v0.y); pk.y = pk2(v0.z, v0.w);
                pk.z = pk2(v1.x, v1.y); pk.w = pk2(v1.z, v1.w);
                *(uint4*)((char*)lds + row * 128 + swz) = pk;
            } else {
                f32x4 v = *(const f32x4*)((const u16*)Av + (size_t)row_g * K + k0 + g * 8);
                *(f32x4*)((char*)lds + row * 128 + swz) = v;
            }
        }
        #pragma unroll
        for (int s = 0; s < 4; ++s) {
            int idx = tid + s * 256;
            int row = idx >> 3, g = idx & 7;
            int row_g = n0 + row; if (row_g >= N) row_g = N - 1;
            f32x4 v = *(const f32x4*)(B + (size_t)row_g * K + k0 + g * 8);
            *(f32x4*)((char*)lds + 8192 + row * 128 + ((g << 4) ^ ((row & 7) << 4))) = v;
        }
        __syncthreads();
        #pragma unroll
        for (int ks = 0; ks < 2; ++ks) {
            const int off = (ks * 64 + ((lane >> 4) << 4)) ^ ((lane & 7) << 4);
            const int ra = lane & 15;
            bf16x8 af[2], bfr[4];
            #pragma unroll
            for (int i = 0; i < 2; ++i)
                af[i] = *(bf16x8*)((char*)lds + (wr * 32 + i * 16 + ra) * 128 + off);
            #pragma unroll
            for (int j = 0; j < 4; ++j)
                bfr[j] = *(bf16x8*)((char*)lds + 8192 + (wc * 64 + j * 16 + ra) * 128 + off);
            #pragma unroll
            for (int i = 0; i < 2; ++i)
                #pragma unroll
                for (int j = 0; j < 4; ++j)
                    acc[i][j] = __builtin_amdgcn_mfma_f32_16x16x32_bf16(af[i], bfr[j], acc[i][j], 0, 0, 0);
        }
        __syncthreads();
    }

    const int cr = lane >> 4, ccol = lane & 15;
    #pragma unroll
    for (int i = 0; i < 2; ++i) {
        #pragma unroll
        for (int j = 0; j < 4; ++j) {
            int colg = n0 + wc * 64 + j * 16 + ccol;
            if (colg >= N) continue;
            float badd = bias ? bias[colg] : 0.f;
            #pragma unroll
            for (int reg = 0; reg < 4; ++reg) {
                int rowg = m0 + wr * 32 + i * 16 + cr * 4 + reg;
                if (rowg >= M) continue;
                float v = acc[i][j][reg] + badd;
                if (rowscale) v *= rowscale[rowg];
                Cb[(size_t)rowg * N + colg] = f2b(v);
            }
        }
    }
}

// ================= mega-fused 4-layer graph transformer ======================
// Block = 1 sequence (64 rows), 512 threads / 8 waves, both types in one grid.
// 4 barriers/layer. Pack-write swizzle folds c (conflict-reduced octets);
// u-phase float4 ctx reads, direct wfT2 loads (NO register-array prefetch —
// round-11 lesson: runtime-indexed arrays spill to scratch, +240MB traffic).
__global__ __launch_bounds__(512, 4) void fused_transformer_kernel(
    const float* __restrict__ gh, const int* __restrict__ dg_seqs,
    const int* __restrict__ pt_seqs,
    const u16* __restrict__ wrN,   // [8][16 gn][8 kc][64 lane][8] bf16
    const u32* __restrict__ wfT2,  // [8][128 d2][256 n] packed bf16 pairs
    const float* __restrict__ ar,  // [8][128]
    const float* __restrict__ lng, const float* __restrict__ lnb,  // [8][256]
    float* __restrict__ embT)      // [2048,256]
{
    __shared__ u16 ldsA[64 * 256];       // 32KB: [c:4][row:64][128B swizzled]
    __shared__ float scoreH[2][64];      // per-head accumulated scores
    __shared__ float ctxS[256];
    __shared__ float uS[2][256];

    const int tid = threadIdx.x;
    const int bx = blockIdx.x;
    const int t = bx >> 10, s = bx & 1023;
    const int r = tid >> 3, o8 = tid & 7;        // row 0..63, col-octant 0..7
    const int wid = tid >> 6, lane = tid & 63;
    const int hd = wid >> 2;                     // head (waves 0-3 / 4-7)
    const int g4 = lane >> 4, cl = lane & 15;

    const int* seqs = t ? pt_seqs : dg_seqs;
    const int un = tid & 255, uhalf = tid >> 8;  // u-matvec assignment

    // ---- gather h0 (thread's 32 cols of its row) ----
    float4 y[8];
    {
        int node = seqs[s * 64 + r];
        const float* src = gh + (size_t)node * 256 + o8 * 32;
        #pragma unroll
        for (int v = 0; v < 8; ++v) y[v] = *(const float4*)(src + v * 4);
    }

    for (int l = 0; l < 4; ++l) {
        const int li = t * 4 + l;

        // ---- pack y -> swizzled bf16 A-LDS (c folded into XOR); zero scoreH --
        {
            const int c = o8 >> 1, gb = (o8 & 1) * 4;
            #pragma unroll
            for (int gg = 0; gg < 4; ++gg) {
                float4 a = y[2 * gg], b = y[2 * gg + 1];
                uint4 pk;
                pk.x = pk2(a.x, a.y); pk.y = pk2(a.z, a.w);
                pk.z = pk2(b.x, b.y); pk.w = pk2(b.z, b.w);
                int g = gb + gg;
                int off = ((g << 4) ^ ((r & 7) << 4)) ^ (c << 4);
                *(uint4*)((char*)ldsA + c * 8192 + r * 128 + off) = pk;
            }
            if (tid < 128) ((float*)scoreH)[tid] = 0.f;
        }
        __syncthreads();   // B1

        // ---- fr = h @ wr^T : wave wid -> cols wid*32..+31, rows 0..63 ----
        f32x4 acc[4][2] = {};
        {
            const u16* wrl = wrN + (size_t)li * 65536;
            const int ra = lane & 15;
            #pragma unroll
            for (int kc = 0; kc < 8; ++kc) {
                const int c = kc >> 1, ks = kc & 1;
                const int off = ((ks * 64 + ((lane >> 4) << 4)) ^ ((lane & 7) << 4)) ^ (c << 4);
                bf16x8 af[4], bfr[2];
                #pragma unroll
                for (int i = 0; i < 4; ++i)
                    af[i] = *(bf16x8*)((char*)ldsA + c * 8192 + (i * 16 + ra) * 128 + off);
                #pragma unroll
                for (int j = 0; j < 2; ++j)
                    bfr[j] = *(const bf16x8*)(wrl + ((size_t)((wid * 2 + j) * 8 + kc) << 9) + lane * 8);
                #pragma unroll
                for (int i = 0; i < 4; ++i)
                    #pragma unroll
                    for (int j = 0; j < 2; ++j)
                        acc[i][j] = __builtin_amdgcn_mfma_f32_16x16x32_bf16(af[i], bfr[j], acc[i][j], 0, 0, 0);
            }
        }

        // ---- scores over this wave's 32 cols -> DPP reduce -> atomicAdd ----
        {
            const float* arl = ar + li * 128;
            float arj[2];
            #pragma unroll
            for (int j = 0; j < 2; ++j) arj[j] = arl[(wid & 3) * 32 + j * 16 + cl];
            #pragma unroll
            for (int i = 0; i < 4; ++i)
                #pragma unroll
                for (int reg = 0; reg < 4; ++reg) {
                    float sc;
                    {
                        float x0 = acc[i][0][reg], x1 = acc[i][1][reg];
                        sc = (x0 >= 0.f ? x0 : 0.01f * x0) * arj[0]
                           + (x1 >= 0.f ? x1 : 0.01f * x1) * arj[1];
                    }
                    sc = sum16_dpp(sc);
                    if (cl == 0) atomicAdd(&scoreH[hd][i * 16 + g4 * 4 + reg], sc);
                }
        }
        __syncthreads();   // B2

        // ---- softmax in-register: lane's 16 rows depend only on g4 ----
        float p[4][4];
        {
            const float* sc = scoreH[hd];
            #pragma unroll
            for (int i = 0; i < 4; ++i)
                *(float4*)p[i] = *(const float4*)(sc + i * 16 + g4 * 4);
            float mx = -1e30f;
            #pragma unroll
            for (int i = 0; i < 4; ++i)
                #pragma unroll
                for (int reg = 0; reg < 4; ++reg) mx = fmaxf(mx, p[i][reg]);
            mx = fmaxf(mx, __shfl_xor(mx, 16, 64));
            mx = fmaxf(mx, __shfl_xor(mx, 32, 64));
            float sme = 0.f;
            #pragma unroll
            for (int i = 0; i < 4; ++i)
                #pragma unroll
                for (int reg = 0; reg < 4; ++reg) {
                    p[i][reg] = __expf(p[i][reg] - mx);
                    sme += p[i][reg];
                }
            sme += __shfl_xor(sme, 16, 64);
            sme += __shfl_xor(sme, 32, 64);
            float inv = 1.f / sme;
            #pragma unroll
            for (int i = 0; i < 4; ++i)
                #pragma unroll
                for (int reg = 0; reg < 4; ++reg) p[i][reg] *= inv;
        }

        // ---- ctx over wave's 32 cols ----
        {
            #pragma unroll
            for (int j = 0; j < 2; ++j) {
                float c = 0.f;
                #pragma unroll
                for (int i = 0; i < 4; ++i)
                    #pragma unroll
                    for (int reg = 0; reg < 4; ++reg)
                        c = fmaf(p[i][reg], acc[i][j][reg], c);
                c += __shfl_xor(c, 16, 64);
                c += __shfl_xor(c, 32, 64);
                if (g4 == 0) ctxS[wid * 32 + j * 16 + cl] = c;
            }
        }
        __syncthreads();   // B3

        // ---- u[n] = sum_d ctx[d]*wf[n][d]; 4 accumulators, float4 ctx reads --
        {
            const u32* wp = wfT2 + (size_t)li * 32768 + (size_t)uhalf * 16384 + un;
            const float* cx = ctxS + uhalf * 128;
            float ua0 = 0.f, ua1 = 0.f, ua2 = 0.f, ua3 = 0.f;
            #pragma unroll 4
            for (int d2 = 0; d2 < 64; d2 += 4) {
                u32 w0 = wp[(size_t)(d2 + 0) * 256];
                u32 w1 = wp[(size_t)(d2 + 1) * 256];
                u32 w2 = wp[(size_t)(d2 + 2) * 256];
                u32 w3 = wp[(size_t)(d2 + 3) * 256];
                float4 c0 = *(const float4*)(cx + 2 * d2);
                float4 c1 = *(const float4*)(cx + 2 * d2 + 4);
                ua0 = fmaf(c0.x, b2f_lo(w0), ua0);
                ua0 = fmaf(c0.y, b2f_hi(w0), ua0);
                ua1 = fmaf(c0.z, b2f_lo(w1), ua1);
                ua1 = fmaf(c0.w, b2f_hi(w1), ua1);
                ua2 = fmaf(c1.x, b2f_lo(w2), ua2);
                ua2 = fmaf(c1.y, b2f_hi(w2), ua2);
                ua3 = fmaf(c1.z, b2f_lo(w3), ua3);
                ua3 = fmaf(c1.w, b2f_hi(w3), ua3);
            }
            uS[uhalf][un] = (ua0 + ua1) + (ua2 + ua3);
        }
        __syncthreads();   // B4

        // ---- h = LN(h + u) (8 threads per row; DPP sum over 8 lanes) ----
        {
            #pragma unroll
            for (int v = 0; v < 8; ++v) {
                int c0 = o8 * 32 + v * 4;
                float4 u0 = *(const float4*)&uS[0][c0];
                float4 u1 = *(const float4*)&uS[1][c0];
                y[v].x += u0.x + u1.x; y[v].y += u0.y + u1.y;
                y[v].z += u0.z + u1.z; y[v].w += u0.w + u1.w;
            }
            float sm = 0.f, qq = 0.f;
            #pragma unroll
            for (int v = 0; v < 8; ++v) {
                sm += y[v].x + y[v].y + y[v].z + y[v].w;
                qq += y[v].x * y[v].x + y[v].y * y[v].y + y[v].z * y[v].z + y[v].w * y[v].w;
            }
            sm = sum8_dpp(sm);
            qq = sum8_dpp(qq);
            float mean = sm * (1.f / 256.f);
            float var = qq * (1.f / 256.f) - mean * mean;
            float inv = rsqrtf(var + 1e-5f);
            const float* gl = lng + li * 256 + o8 * 32;
            const float* bl = lnb + li * 256 + o8 * 32;
            if (l < 3) {
                #pragma unroll
                for (int v = 0; v < 8; ++v) {
                    float4 gv = *(const float4*)(gl + v * 4);
                    float4 bv = *(const float4*)(bl + v * 4);
                    y[v].x = (y[v].x - mean) * inv * gv.x + bv.x;
                    y[v].y = (y[v].y - mean) * inv * gv.y + bv.y;
                    y[v].z = (y[v].z - mean) * inv * gv.z + bv.z;
                    y[v].w = (y[v].w - mean) * inv * gv.w + bv.w;
                }
            } else if (r == 0) {
                float* dst = embT + (size_t)(t * 1024 + s) * 256 + o8 * 32;
                #pragma unroll
                for (int v = 0; v < 8; ++v) {
                    float4 gv = *(const float4*)(gl + v * 4);
                    float4 bv = *(const float4*)(bl + v * 4);
                    float4 o;
                    o.x = (y[v].x - mean) * inv * gv.x + bv.x;
                    o.y = (y[v].y - mean) * inv * gv.y + bv.y;
                    o.z = (y[v].z - mean) * inv * gv.z + bv.z;
                    o.w = (y[v].w - mean) * inv * gv.w + bv.w;
                    *(float4*)(dst + v * 4) = o;
                }
            }
        }
        // no end barrier: ordering provided by B2..B4 (round-8 analysis)
    }
}

// ================= fp32 tiled GEMM (small M), dual-set via blockIdx.z ========
template<bool BT>
__global__ __launch_bounds__(256) void gemm_kernel(
    const float* __restrict__ A, const float* __restrict__ B,
    const float* __restrict__ bias, const float* __restrict__ rowscale,
    float* __restrict__ C,
    int M, int N, int K, int lda, int ldb, int ldc, int coff, int act,
    const float* __restrict__ A1, const float* __restrict__ B1,
    const float* __restrict__ bias1, float* __restrict__ C1, int coff1)
{
    if (blockIdx.z) { A = A1; B = B1; bias = bias1; C = C1; coff = coff1; }
    __shared__ float As[32][64 + 4];
    __shared__ float Bs[32][64 + 4];
    const int tid = threadIdx.x;
    const int m0 = blockIdx.y * 64;
    const int n0 = blockIdx.x * 64;
    const int ty = tid >> 4, tx = tid & 15;
    float acc[4][4] = {};
    for (int k0 = 0; k0 < K; k0 += 32) {
        #pragma unroll
        for (int r = 0; r < 2; ++r) {
            int f4 = tid + r * 256;
            int arw = f4 >> 3, af = (f4 & 7) << 2;
            float4 v = make_float4(0.f, 0.f, 0.f, 0.f);
            int grow = m0 + arw;
            if (grow < M) {
                v = *(const float4*)(A + (size_t)grow * lda + k0 + af);
                if (rowscale) { float s = rowscale[grow]; v.x *= s; v.y *= s; v.z *= s; v.w *= s; }
            }
            As[af + 0][arw] = v.x; As[af + 1][arw] = v.y; As[af + 2][arw] = v.z; As[af + 3][arw] = v.w;
        }
        #pragma unroll
        for (int r = 0; r < 2; ++r) {
            int f4 = tid + r * 256;
            int col = f4 >> 3, kf = (f4 & 7) << 2;
            float4 v = make_float4(0.f, 0.f, 0.f, 0.f);
            if (n0 + col < N) v = *(const float4*)(B + (size_t)(n0 + col) * ldb + k0 + kf);
            Bs[kf + 0][col] = v.x; Bs[kf + 1][col] = v.y; Bs[kf + 2][col] = v.z; Bs[kf + 3][col] = v.w;
        }
        __syncthreads();
        #pragma unroll
        for (int kk = 0; kk < 32; ++kk) {
            float4 a4 = *(const float4*)&As[kk][ty << 2];
            float4 b4 = *(const float4*)&Bs[kk][tx << 2];
            float a[4] = {a4.x, a4.y, a4.z, a4.w};
            float b[4] = {b4.x, b4.y, b4.z, b4.w};
            #pragma unroll
            for (int i = 0; i < 4; ++i)
                #pragma unroll
                for (int j = 0; j < 4; ++j)
                    acc[i][j] = fmaf(a[i], b[j], acc[i][j]);
        }
        __syncthreads();
    }
    #pragma unroll
    for (int i = 0; i < 4; ++i) {
        int row = m0 + (ty << 2) + i;
        if (row >= M) continue;
        #pragma unroll
        for (int j = 0; j < 4; ++j) {
            int col = n0 + (tx << 2) + j;
            if (col >= N) continue;
            float v = acc[i][j];
            if (bias) v += bias[col];
            if (act == 1) v = fmaxf(v, 0.f);
            else if (act == 2) v = (v > 0.f) ? v : expm1f(v);
            C[(size_t)row * ldc + coff + col] = v;
        }
    }
}

// ================= merged converts (one dispatch, 2048 blocks) ===============
__global__ __launch_bounds__(256) void conv_all_kernel(
    const float* __restrict__ fc_w0, const float* __restrict__ fc_w1,
    const float* __restrict__ gcn_w, const float* __restrict__ gt_wr,
    const float* __restrict__ gt_wf,
    u16* __restrict__ fcw_b, u16* __restrict__ gcnw_b,
    u16* __restrict__ wrN, u32* __restrict__ wfT2)
{
    int bid = blockIdx.x, tid = threadIdx.x;
    if (bid < 256) {
        const float* src = bid < 128 ? fc_w0 : fc_w1;
        u16* dst = fcw_b + (bid < 128 ? 0 : 131072);
        int i = ((bid & 127) * 256 + tid) * 4;
        float4 v = *(const float4*)(src + i);
        *(uint2*)(dst + i) = make_uint2(pk2(v.x, v.y), pk2(v.z, v.w));
    } else if (bid < 768) {
        int idx = (bid - 256) * 256 + tid;   // 0..131071
        int l = idx >> 16, rem = idx & 65535;
        int k = rem >> 8, n = rem & 255;
        gcnw_b[(size_t)l * 65536 + n * 256 + k] = f2b(gcn_w[(size_t)l * 65536 + k * 256 + n]);
    } else if (bid < 1024) {
        int idx = (bid - 768) * 256 + tid;   // 0..65535
        int lane = idx & 63;
        int kc = (idx >> 6) & 7;
        int gn = (idx >> 9) & 15;
        int l = idx >> 13;
        int row = gn * 16 + (lane & 15);
        int k0 = kc * 32 + (lane >> 4) * 8;
        const float* src = gt_wr + ((size_t)l * 256 + row) * 256 + k0;
        float4 v0 = *(const float4*)src;
        float4 v1 = *(const float4*)(src + 4);
        uint4 pk;
        pk.x = pk2(v0.x, v0.y); pk.y = pk2(v0.z, v0.w);
        pk.z = pk2(v1.x, v1.y); pk.w = pk2(v1.z, v1.w);
        *(uint4*)(wrN + (size_t)idx * 8) = pk;
    } else {
        int idx = (bid - 1024) * 256 + tid;  // 0..262143
        int n = idx & 255;
        int d2 = (idx >> 8) & 127;
        int l = idx >> 15;
        const float* src = gt_wf + ((size_t)l * 256 + n) * 256 + 2 * d2;
        wfT2[idx] = pk2(src[0], src[1]);
    }
}

// ================= CSR build (4 edges/thread, pipelined atomics) =============
#define EDGE_CAP 128
__global__ __launch_bounds__(256) void bucket_fill_kernel(
    const int* __restrict__ src, const int* __restrict__ dst,
    int* __restrict__ ebuf, int* __restrict__ cursor, int* __restrict__ cnt_out, int ne)
{
    int e0 = (blockIdx.x * 256 + threadIdx.x) * 4;
    if (e0 >= ne) return;
    int4 s4 = *(const int4*)(src + e0);
    int4 d4 = *(const int4*)(dst + e0);
    atomicAdd(&cnt_out[s4.x], 1);
    atomicAdd(&cnt_out[s4.y], 1);
    atomicAdd(&cnt_out[s4.z], 1);
    atomicAdd(&cnt_out[s4.w], 1);
    int p0 = atomicAdd(&cursor[d4.x], 1);
    int p1 = atomicAdd(&cursor[d4.y], 1);
    int p2 = atomicAdd(&cursor[d4.z], 1);
    int p3 = atomicAdd(&cursor[d4.w], 1);
    if (p0 < EDGE_CAP) ebuf[(size_t)d4.x * EDGE_CAP + p0] = s4.x;
    if (p1 < EDGE_CAP) ebuf[(size_t)d4.y * EDGE_CAP + p1] = s4.y;
    if (p2 < EDGE_CAP) ebuf[(size_t)d4.z * EDGE_CAP + p2] = s4.z;
    if (p3 < EDGE_CAP) ebuf[(size_t)d4.w * EDGE_CAP + p3] = s4.w;
}
__global__ __launch_bounds__(256) void deg_fin_kernel(const int* __restrict__ cnt, float* __restrict__ dinv, int n) {
    int i = blockIdx.x * 256 + threadIdx.x;
    if (i < n) dinv[i] = rsqrtf(fmaxf((float)cnt[i], 1.0f));
}

// ================= CSR aggregate, skips dead outputs per layer ===============
template<bool WF, bool WB>
__global__ __launch_bounds__(256) void csr_agg_kernel(
    const u16* __restrict__ x, const int* __restrict__ ebuf,
    const int* __restrict__ deg, float* __restrict__ outf, u16* __restrict__ outb, int nnodes)
{
    int n = blockIdx.x * 4 + (threadIdx.x >> 6);
    if (n >= nnodes) return;
    int lane = threadIdx.x & 63;
    int d = deg[n];
    float dinv = rsqrtf(fmaxf((float)d, 1.0f));
    if (d > EDGE_CAP) d = EDGE_CAP;
    const int* eb = ebuf + (size_t)n * EDGE_CAP;
    const int co = lane << 2;
    float a0 = 0.f, a1 = 0.f, a2 = 0.f, a3 = 0.f;
    int k = 0;
    for (; k + 4 <= d; k += 4) {
        int4 s4 = *(const int4*)(eb + k);
        uint2 va = *(const uint2*)(x + (size_t)s4.x * 256 + co);
        uint2 vb = *(const uint2*)(x + (size_t)s4.y * 256 + co);
        uint2 vc = *(const uint2*)(x + (size_t)s4.z * 256 + co);
        uint2 vd = *(const uint2*)(x + (size_t)s4.w * 256 + co);
        a0 += b2f_lo(va.x) + b2f_lo(vb.x) + b2f_lo(vc.x) + b2f_lo(vd.x);
        a1 += b2f_hi(va.x) + b2f_hi(vb.x) + b2f_hi(vc.x) + b2f_hi(vd.x);
        a2 += b2f_lo(va.y) + b2f_lo(vb.y) + b2f_lo(vc.y) + b2f_lo(vd.y);
        a3 += b2f_hi(va.y) + b2f_hi(vb.y) + b2f_hi(vc.y) + b2f_hi(vd.y);
    }
    for (; k < d; ++k) {
        int s = eb[k];
        uint2 v = *(const uint2*)(x + (size_t)s * 256 + co);
        a0 += b2f_lo(v.x); a1 += b2f_hi(v.x);
        a2 += b2f_lo(v.y); a3 += b2f_hi(v.y);
    }
    a0 = fmaxf(a0 * dinv, 0.f); a1 = fmaxf(a1 * dinv, 0.f);
    a2 = fmaxf(a2 * dinv, 0.f); a3 = fmaxf(a3 * dinv, 0.f);
    if (WF) *(float4*)(outf + (size_t)n * 256 + co) = make_float4(a0, a1, a2, a3);
    if (WB) *(uint2*)(outb + (size_t)n * 256 + co) = make_uint2(pk2(a0, a1), pk2(a2, a3));
}

// ================= fused MLP tail: m2 = relu(m1@w2^T+b2); out = sigmoid(m2.w3+b3)
__global__ __launch_bounds__(256) void mlp_tail_kernel(
    const float* __restrict__ m1, const float* __restrict__ w2,
    const float* __restrict__ b2, const float* __restrict__ w3,
    const float* __restrict__ b3, float* __restrict__ out)
{
    __shared__ float rowS[4][256];
    const int w = threadIdx.x >> 6, lane = threadIdx.x & 63;
    const int row = blockIdx.x * 4 + w;
    *(float4*)&rowS[w][lane * 4] = *(const float4*)(m1 + (size_t)row * 256 + lane * 4);
    __syncthreads();
    const float* rp = rowS[w];
    float v0 = b2[lane], v1 = b2[64 + lane];
    const float* wa = w2 + (size_t)lane * 256;
    const float* wb = w2 + (size_t)(64 + lane) * 256;
    #pragma unroll 8
    for (int d = 0; d < 256; d += 4) {
        float4 rv = *(const float4*)(rp + d);
        float4 a = *(const float4*)(wa + d);
        float4 b = *(const float4*)(wb + d);
        v0 = fmaf(rv.x, a.x, v0); v0 = fmaf(rv.y, a.y, v0);
        v0 = fmaf(rv.z, a.z, v0); v0 = fmaf(rv.w, a.w, v0);
        v1 = fmaf(rv.x, b.x, v1); v1 = fmaf(rv.y, b.y, v1);
        v1 = fmaf(rv.z, b.z, v1); v1 = fmaf(rv.w, b.w, v1);
    }
    v0 = fmaxf(v0, 0.f); v1 = fmaxf(v1, 0.f);
    float s = v0 * w3[lane] + v1 * w3[64 + lane];
    s = wave_sum(s);
    if (lane == 0) out[row] = 1.f / (1.f + expf(-(s + b3[0])));
}

static inline int cdiv(int a, int b) { return (a + b - 1) / b; }

extern "C" void kernel_launch(void* const* d_in, const int* in_sizes, int n_in,
                              void* d_out, int out_size, void* d_ws, size_t ws_size,
                              hipStream_t stream)
{
    const float* feat0   = (const float*)d_in[0];
    const float* feat1   = (const float*)d_in[1];
    const float* fc_w0   = (const float*)d_in[2];
    const float* fc_b0   = (const float*)d_in[3];
    const float* fc_w1   = (const float*)d_in[4];
    const float* fc_b1   = (const float*)d_in[5];
    const float* gcn_w   = (const float*)d_in[6];
    const int*   edge_src= (const int*)d_in[7];
    const int*   edge_dst= (const int*)d_in[8];
    const int*   dg_seqs = (const int*)d_in[9];
    const int*   pt_seqs = (const int*)d_in[10];
    // 11 type_emb, 12 node_type: dead; 13 gt_wl, 15 gt_al: dead (softmax cancellation)
    const float* gt_wr   = (const float*)d_in[14];
    const float* gt_ar   = (const float*)d_in[16];
    const float* gt_wf   = (const float*)d_in[17];
    const float* ln_g    = (const float*)d_in[18];
    const float* ln_b    = (const float*)d_in[19];
    const float* proj_d_w= (const float*)d_in[20];
    const float* proj_d_b= (const float*)d_in[21];
    const float* proj_p_w= (const float*)d_in[22];
    const float* proj_p_b= (const float*)d_in[23];
    const float* ml_w1   = (const float*)d_in[24];
    const float* ml_b1   = (const float*)d_in[25];
    const float* ml_w2   = (const float*)d_in[26];
    const float* ml_b2   = (const float*)d_in[27];
    const float* ml_w3   = (const float*)d_in[28];
    const float* ml_b3   = (const float*)d_in[29];
    float* out = (float*)d_out;

    // ---- workspace layout (f32 units) ----
    float* base  = (float*)d_ws;
    float* gh    = base;                      // 10,240,000
    float* gcnR  = gh + 10240000;             // GCN-phase region (15,440,000)
    float* dego  = gcnR + 15440000;           // 40,000
    float* embT  = dego + 40000;              // 524,288 (both types)
    float* t1    = embT + 524288;             // 524,288 (both types)
    float* mx    = t1 + 524288;               // 524,288
    float* m1    = mx + 524288;               // 262,144
    float* m2    = m1 + 262144;               // 131,072 (unused, kept for layout)
    float* wreg  = m2 + 131072;               // converted weights

    u16* tmp_b   = (u16*)gcnR;                        // 10,240,000 bf16
    int* ebuf    = (int*)(gcnR + 5120000);            // 5,120,000 int
    int* cursor  = ebuf + (size_t)40000 * EDGE_CAP;   // 40,000
    int* cnt_out = cursor + 40000;                    // 40,000
    u16* gh_b    = (u16*)(gcnR + 10320000);           // 10,240,000 bf16

    u16* fcw_b   = (u16*)wreg;                // 262,144 u16
    u16* gcnw_b  = fcw_b + 262144;            // 131,072 u16
    u16* wrN     = gcnw_b + 131072;           // 524,288 u16 (8 layers x 65,536)
    u32* wfT2    = (u32*)(wrN + 524288);      // 262,144 u32 (8 layers x 32,768)

    // ---- merged weight converts (single dispatch) ----
    conv_all_kernel<<<2048, 256, 0, stream>>>(
        fc_w0, fc_w1, gcn_w, gt_wr, gt_wf, fcw_b, gcnw_b, wrN, wfT2);

    // ---- FC projections (merged dual GEMM via blockIdx.z) -> gh_b ----
    mfma_gemm_kernel<true><<<dim3(2, cdiv(20000, 64), 2), 256, 0, stream>>>(
        feat0, fcw_b, fc_b0, nullptr, gh_b, 20000, 256, 512,
        feat1, fcw_b + 131072, fc_b1, gh_b + (size_t)20000 * 256);

    // ---- CSR build (once) ----
    hipMemsetAsync(cursor, 0, 80000 * sizeof(int), stream);
    bucket_fill_kernel<<<625, 256, 0, stream>>>(edge_src, edge_dst, ebuf, cursor, cnt_out, 640000);
    deg_fin_kernel<<<cdiv(40000, 256), 256, 0, stream>>>(cnt_out, dego, 40000);

    // ---- 2x GCN (layer 0 writes bf16 only; layer 1 writes f32 only) ----
    mfma_gemm_kernel<false><<<dim3(2, cdiv(40000, 64), 1), 256, 0, stream>>>(
        gh_b, gcnw_b, nullptr, dego, tmp_b, 40000, 256, 256,
        gh_b, gcnw_b, nullptr, tmp_b);
    csr_agg_kernel<false, true><<<10000, 256, 0, stream>>>(tmp_b, ebuf, cursor, gh, gh_b, 40000);
    mfma_gemm_kernel<false><<<dim3(2, cdiv(40000, 64), 1), 256, 0, stream>>>(
        gh_b, gcnw_b + 65536, nullptr, dego, tmp_b, 40000, 256, 256,
        gh_b, gcnw_b, nullptr, tmp_b);
    csr_agg_kernel<true, false><<<10000, 256, 0, stream>>>(tmp_b, ebuf, cursor, gh, gh_b, 40000);

    // ---- mega-fused graph transformer, both types in one dispatch ----
    fused_transformer_kernel<<<2048, 512, 0, stream>>>(
        gh, dg_seqs, pt_seqs, wrN, wfT2, gt_ar, ln_g, ln_b, embT);

    // ---- proj heads (both types per dispatch via blockIdx.z) ----
    gemm_kernel<true><<<dim3(4, 16, 2), 256, 0, stream>>>(
        embT, proj_d_w, proj_d_b, nullptr, t1, 1024, 256, 256, 256, 256, 256, 0, 2,
        embT + 262144, proj_p_w, proj_p_b, t1 + 262144, 0);
    gemm_kernel<true><<<dim3(4, 16, 2), 256, 0, stream>>>(
        t1, proj_d_w + 65536, proj_d_b + 256, nullptr, mx, 1024, 256, 256, 256, 256, 512, 0, 0,
        t1 + 262144, proj_p_w + 65536, proj_p_b + 256, mx, 256);

    // ---- predict MLP: first GEMM, then fused tail ----
    gemm_kernel<true><<<dim3(4, 16, 1), 256, 0, stream>>>(
        mx, ml_w1, ml_b1, nullptr, m1, 1024, 256, 512, 512, 512, 256, 0, 1,
        mx, ml_w1, ml_b1, m1, 0);
    mlp_tail_kernel<<<256, 256, 0, stream>>>(m1, ml_w2, ml_b2, ml_w3, ml_b3, out);
}

// Round 13
// 596.507 us; speedup vs baseline: 1.2148x; 1.0686x over previous
//
#include <hip/hip_runtime.h>
#include <hip/hip_bf16.h>
#include <math.h>

typedef unsigned int u32;
typedef unsigned short u16;
typedef __attribute__((ext_vector_type(8))) short bf16x8;
typedef __attribute__((ext_vector_type(4))) float f32x4;

__device__ __forceinline__ float b2f(u16 u) { union { u32 i; float f; } c; c.i = ((u32)u) << 16; return c.f; }
__device__ __forceinline__ u16 f2b(float f) { __hip_bfloat16 h = __float2bfloat16(f); u16 r; __builtin_memcpy(&r, &h, 2); return r; }
__device__ __forceinline__ float b2f_lo(u32 w) { union { u32 i; float f; } c; c.i = w << 16; return c.f; }
__device__ __forceinline__ float b2f_hi(u32 w) { union { u32 i; float f; } c; c.i = w & 0xffff0000u; return c.f; }
__device__ __forceinline__ u32 pk2(float a, float b) { return (u32)f2b(a) | ((u32)f2b(b) << 16); }

__device__ __forceinline__ float wave_sum(float v) {
    #pragma unroll
    for (int off = 32; off > 0; off >>= 1) v += __shfl_xor(v, off, 64);
    return v;
}

// ---- DPP helpers (VALU pipe) ----
template<int CTRL>
__device__ __forceinline__ float dpp_addf(float v) {
    int y = __builtin_amdgcn_update_dpp(0, __builtin_bit_cast(int, v), CTRL, 0xF, 0xF, true);
    return v + __builtin_bit_cast(float, y);
}
template<int CTRL>
__device__ __forceinline__ float dpp_movf(float v) {
    int y = __builtin_amdgcn_update_dpp(0, __builtin_bit_cast(int, v), CTRL, 0xF, 0xF, true);
    return __builtin_bit_cast(float, y);
}
__device__ __forceinline__ float sum16_dpp(float v) {
    v = dpp_addf<0xB1>(v);
    v = dpp_addf<0x4E>(v);
    v = dpp_addf<0x141>(v);
    v = dpp_addf<0x140>(v);
    return v;
}
__device__ __forceinline__ float sum8_dpp(float v) {
    v = dpp_addf<0xB1>(v);
    v = dpp_addf<0x4E>(v);
    v = dpp_addf<0x141>(v);
    return v;
}

// ================= bf16 MFMA GEMM (64x128 tile, 4 waves of 32x64) ============
template<bool AF32>
__global__ __launch_bounds__(256) void mfma_gemm_kernel(
    const void* __restrict__ Av, const u16* __restrict__ B,
    const float* __restrict__ bias, const float* __restrict__ rowscale,
    u16* __restrict__ Cb, int M, int N, int K,
    const void* __restrict__ Av1, const u16* __restrict__ B1,
    const float* __restrict__ bias1, u16* __restrict__ Cb1)
{
    if (blockIdx.z) { Av = Av1; B = B1; bias = bias1; Cb = Cb1; }
    __shared__ u16 lds[(64 + 128) * 64];   // A bytes [0,8192), B bytes [8192,24576)
    const int tid = threadIdx.x;
    const int wid = tid >> 6, lane = tid & 63;
    const int wr = wid >> 1, wc = wid & 1;
    const int m0 = blockIdx.y * 64, n0 = blockIdx.x * 128;

    f32x4 acc[2][4] = {};

    for (int k0 = 0; k0 < K; k0 += 64) {
        #pragma unroll
        for (int s = 0; s < 2; ++s) {
            int idx = tid + s * 256;
            int row = idx >> 3, g = idx & 7;
            int row_g = m0 + row; if (row_g >= M) row_g = M - 1;
            int swz = ((g << 4) ^ ((row & 7) << 4));
            if (AF32) {
                const float* src = (const float*)Av + (size_t)row_g * K + k0 + g * 8;
                float4 v0 = *(const float4*)src;
                float4 v1 = *(const float4*)(src + 4);
                uint4 pk;
                pk.x = pk2(v0.x, v0.y); pk.y = pk2(v0.z, v0.w);
                pk.z = pk2(v1.x, v1.y); pk.w = pk2(v1.z, v1.w);
                *(uint4*)((char*)lds + row * 128 + swz) = pk;
            } else {
                f32x4 v = *(const f32x4*)((const u16*)Av + (size_t)row_g * K + k0 + g * 8);
                *(f32x4*)((char*)lds + row * 128 + swz) = v;
            }
        }
        #pragma unroll
        for (int s = 0; s < 4; ++s) {
            int idx = tid + s * 256;
            int row = idx >> 3, g = idx & 7;
            int row_g = n0 + row; if (row_g >= N) row_g = N - 1;
            f32x4 v = *(const f32x4*)(B + (size_t)row_g * K + k0 + g * 8);
            *(f32x4*)((char*)lds + 8192 + row * 128 + ((g << 4) ^ ((row & 7) << 4))) = v;
        }
        __syncthreads();
        #pragma unroll
        for (int ks = 0; ks < 2; ++ks) {
            const int off = (ks * 64 + ((lane >> 4) << 4)) ^ ((lane & 7) << 4);
            const int ra = lane & 15;
            bf16x8 af[2], bfr[4];
            #pragma unroll
            for (int i = 0; i < 2; ++i)
                af[i] = *(bf16x8*)((char*)lds + (wr * 32 + i * 16 + ra) * 128 + off);
            #pragma unroll
            for (int j = 0; j < 4; ++j)
                bfr[j] = *(bf16x8*)((char*)lds + 8192 + (wc * 64 + j * 16 + ra) * 128 + off);
            #pragma unroll
            for (int i = 0; i < 2; ++i)
                #pragma unroll
                for (int j = 0; j < 4; ++j)
                    acc[i][j] = __builtin_amdgcn_mfma_f32_16x16x32_bf16(af[i], bfr[j], acc[i][j], 0, 0, 0);
        }
        __syncthreads();
    }

    const int cr = lane >> 4, ccol = lane & 15;
    #pragma unroll
    for (int i = 0; i < 2; ++i) {
        #pragma unroll
        for (int j = 0; j < 4; ++j) {
            int colg = n0 + wc * 64 + j * 16 + ccol;
            if (colg >= N) continue;
            float badd = bias ? bias[colg] : 0.f;
            #pragma unroll
            for (int reg = 0; reg < 4; ++reg) {
                int rowg = m0 + wr * 32 + i * 16 + cr * 4 + reg;
                if (rowg >= M) continue;
                float v = acc[i][j][reg] + badd;
                if (rowscale) v *= rowscale[rowg];
                Cb[(size_t)rowg * N + colg] = f2b(v);
            }
        }
    }
}

// ================= mega-fused 4-layer graph transformer ======================
// Block = 1 sequence (64 rows), 512 threads / 8 waves, both types in one grid.
// 4 barriers/layer. u = ctx @ wf^T computed on the MFMA pipe (A = ctx row 0,
// garbage rows discarded); ctx packed to bf16 in-register via DPP lane-swap.
__global__ __launch_bounds__(512, 4) void fused_transformer_kernel(
    const float* __restrict__ gh, const int* __restrict__ dg_seqs,
    const int* __restrict__ pt_seqs,
    const u16* __restrict__ wrN,   // [8][16 gn][8 kc][64 lane][8] bf16
    const u16* __restrict__ wfN,   // [8][16 gn][8 kc][64 lane][8] bf16
    const float* __restrict__ ar,  // [8][128]
    const float* __restrict__ lng, const float* __restrict__ lnb,  // [8][256]
    float* __restrict__ embT)      // [2048,256]
{
    __shared__ u16 ldsA[64 * 256];                 // 32KB swizzled A
    __shared__ float scoreH[2][64];                // per-head accumulated scores
    __shared__ __align__(16) u32 ctxB[128];        // ctx packed bf16 pairs
    __shared__ __align__(16) float uS[256];

    const int tid = threadIdx.x;
    const int bx = blockIdx.x;
    const int t = bx >> 10, s = bx & 1023;
    const int r = tid >> 3, o8 = tid & 7;        // row 0..63, col-octant 0..7
    const int wid = tid >> 6, lane = tid & 63;
    const int hd = wid >> 2;                     // head (waves 0-3 / 4-7)
    const int g4 = lane >> 4, cl = lane & 15;

    const int* seqs = t ? pt_seqs : dg_seqs;

    // ---- gather h0 (thread's 32 cols of its row) ----
    float4 y[8];
    {
        int node = seqs[s * 64 + r];
        const float* src = gh + (size_t)node * 256 + o8 * 32;
        #pragma unroll
        for (int v = 0; v < 8; ++v) y[v] = *(const float4*)(src + v * 4);
    }

    for (int l = 0; l < 4; ++l) {
        const int li = t * 4 + l;

        // ---- pack y -> swizzled bf16 A-LDS (c folded into XOR); zero scoreH --
        {
            const int c = o8 >> 1, gb = (o8 & 1) * 4;
            #pragma unroll
            for (int gg = 0; gg < 4; ++gg) {
                float4 a = y[2 * gg], b = y[2 * gg + 1];
                uint4 pk;
                pk.x = pk2(a.x, a.y); pk.y = pk2(a.z, a.w);
                pk.z = pk2(b.x, b.y); pk.w = pk2(b.z, b.w);
                int g = gb + gg;
                int off = ((g << 4) ^ ((r & 7) << 4)) ^ (c << 4);
                *(uint4*)((char*)ldsA + c * 8192 + r * 128 + off) = pk;
            }
            if (tid < 128) ((float*)scoreH)[tid] = 0.f;
        }
        __syncthreads();   // B1

        // ---- fr = h @ wr^T : wave wid -> cols wid*32..+31, rows 0..63 ----
        f32x4 acc[4][2] = {};
        {
            const u16* wrl = wrN + (size_t)li * 65536;
            const int ra = lane & 15;
            #pragma unroll
            for (int kc = 0; kc < 8; ++kc) {
                const int c = kc >> 1, ks = kc & 1;
                const int off = ((ks * 64 + ((lane >> 4) << 4)) ^ ((lane & 7) << 4)) ^ (c << 4);
                bf16x8 af[4], bfr[2];
                #pragma unroll
                for (int i = 0; i < 4; ++i)
                    af[i] = *(bf16x8*)((char*)ldsA + c * 8192 + (i * 16 + ra) * 128 + off);
                #pragma unroll
                for (int j = 0; j < 2; ++j)
                    bfr[j] = *(const bf16x8*)(wrl + ((size_t)((wid * 2 + j) * 8 + kc) << 9) + lane * 8);
                #pragma unroll
                for (int i = 0; i < 4; ++i)
                    #pragma unroll
                    for (int j = 0; j < 2; ++j)
                        acc[i][j] = __builtin_amdgcn_mfma_f32_16x16x32_bf16(af[i], bfr[j], acc[i][j], 0, 0, 0);
            }
        }

        // ---- scores over this wave's 32 cols -> DPP reduce -> atomicAdd ----
        {
            const float* arl = ar + li * 128;
            float arj[2];
            #pragma unroll
            for (int j = 0; j < 2; ++j) arj[j] = arl[(wid & 3) * 32 + j * 16 + cl];
            #pragma unroll
            for (int i = 0; i < 4; ++i)
                #pragma unroll
                for (int reg = 0; reg < 4; ++reg) {
                    float sc;
                    {
                        float x0 = acc[i][0][reg], x1 = acc[i][1][reg];
                        sc = (x0 >= 0.f ? x0 : 0.01f * x0) * arj[0]
                           + (x1 >= 0.f ? x1 : 0.01f * x1) * arj[1];
                    }
                    sc = sum16_dpp(sc);
                    if (cl == 0) atomicAdd(&scoreH[hd][i * 16 + g4 * 4 + reg], sc);
                }
        }
        __syncthreads();   // B2

        // ---- softmax in-register: lane's 16 rows depend only on g4 ----
        float p[4][4];
        {
            const float* sc = scoreH[hd];
            #pragma unroll
            for (int i = 0; i < 4; ++i)
                *(float4*)p[i] = *(const float4*)(sc + i * 16 + g4 * 4);
            float mx = -1e30f;
            #pragma unroll
            for (int i = 0; i < 4; ++i)
                #pragma unroll
                for (int reg = 0; reg < 4; ++reg) mx = fmaxf(mx, p[i][reg]);
            mx = fmaxf(mx, __shfl_xor(mx, 16, 64));
            mx = fmaxf(mx, __shfl_xor(mx, 32, 64));
            float sme = 0.f;
            #pragma unroll
            for (int i = 0; i < 4; ++i)
                #pragma unroll
                for (int reg = 0; reg < 4; ++reg) {
                    p[i][reg] = __expf(p[i][reg] - mx);
                    sme += p[i][reg];
                }
            sme += __shfl_xor(sme, 16, 64);
            sme += __shfl_xor(sme, 32, 64);
            float inv = 1.f / sme;
            #pragma unroll
            for (int i = 0; i < 4; ++i)
                #pragma unroll
                for (int reg = 0; reg < 4; ++reg) p[i][reg] *= inv;
        }

        // ---- ctx over wave's 32 cols -> packed bf16 pairs into ctxB ----
        {
            #pragma unroll
            for (int j = 0; j < 2; ++j) {
                float c = 0.f;
                #pragma unroll
                for (int i = 0; i < 4; ++i)
                    #pragma unroll
                    for (int reg = 0; reg < 4; ++reg)
                        c = fmaf(p[i][reg], acc[i][j][reg], c);
                c += __shfl_xor(c, 16, 64);
                c += __shfl_xor(c, 32, 64);       // all lanes now hold c(cl)
                float cn = dpp_movf<0xB1>(c);      // neighbor (cl^1)'s value
                if (g4 == 0 && (cl & 1) == 0)
                    ctxB[wid * 16 + j * 8 + (cl >> 1)] = pk2(c, cn);
            }
        }
        __syncthreads();   // B3

        // ---- u = ctx @ wf^T on the MFMA pipe (row 0 only is valid) ----
        {
            const u16* wfl = wfN + (size_t)li * 65536;
            f32x4 au0 = {}, au1 = {};
            #pragma unroll
            for (int kc = 0; kc < 8; ++kc) {
                bf16x8 cf = *(bf16x8*)((char*)ctxB + kc * 64 + ((lane >> 4) << 4));
                bf16x8 w0 = *(const bf16x8*)(wfl + ((size_t)((wid * 2 + 0) * 8 + kc) << 9) + lane * 8);
                bf16x8 w1 = *(const bf16x8*)(wfl + ((size_t)((wid * 2 + 1) * 8 + kc) << 9) + lane * 8);
                au0 = __builtin_amdgcn_mfma_f32_16x16x32_bf16(cf, w0, au0, 0, 0, 0);
                au1 = __builtin_amdgcn_mfma_f32_16x16x32_bf16(cf, w1, au1, 0, 0, 0);
            }
            if (lane < 16) {
                uS[wid * 32 + lane] = au0[0];
                uS[wid * 32 + 16 + lane] = au1[0];
            }
        }
        __syncthreads();   // B4

        // ---- h = LN(h + u) (8 threads per row; DPP sum over 8 lanes) ----
        {
            #pragma unroll
            for (int v = 0; v < 8; ++v) {
                float4 uv = *(const float4*)&uS[o8 * 32 + v * 4];
                y[v].x += uv.x; y[v].y += uv.y; y[v].z += uv.z; y[v].w += uv.w;
            }
            float sm = 0.f, qq = 0.f;
            #pragma unroll
            for (int v = 0; v < 8; ++v) {
                sm += y[v].x + y[v].y + y[v].z + y[v].w;
                qq += y[v].x * y[v].x + y[v].y * y[v].y + y[v].z * y[v].z + y[v].w * y[v].w;
            }
            sm = sum8_dpp(sm);
            qq = sum8_dpp(qq);
            float mean = sm * (1.f / 256.f);
            float var = qq * (1.f / 256.f) - mean * mean;
            float inv = rsqrtf(var + 1e-5f);
            const float* gl = lng + li * 256 + o8 * 32;
            const float* bl = lnb + li * 256 + o8 * 32;
            if (l < 3) {
                #pragma unroll
                for (int v = 0; v < 8; ++v) {
                    float4 gv = *(const float4*)(gl + v * 4);
                    float4 bv = *(const float4*)(bl + v * 4);
                    y[v].x = (y[v].x - mean) * inv * gv.x + bv.x;
                    y[v].y = (y[v].y - mean) * inv * gv.y + bv.y;
                    y[v].z = (y[v].z - mean) * inv * gv.z + bv.z;
                    y[v].w = (y[v].w - mean) * inv * gv.w + bv.w;
                }
            } else if (r == 0) {
                float* dst = embT + (size_t)(t * 1024 + s) * 256 + o8 * 32;
                #pragma unroll
                for (int v = 0; v < 8; ++v) {
                    float4 gv = *(const float4*)(gl + v * 4);
                    float4 bv = *(const float4*)(bl + v * 4);
                    float4 o;
                    o.x = (y[v].x - mean) * inv * gv.x + bv.x;
                    o.y = (y[v].y - mean) * inv * gv.y + bv.y;
                    o.z = (y[v].z - mean) * inv * gv.z + bv.z;
                    o.w = (y[v].w - mean) * inv * gv.w + bv.w;
                    *(float4*)(dst + v * 4) = o;
                }
            }
        }
        // no end barrier: ordering provided by B2..B4 (round-8 analysis)
    }
}

// ================= fp32 tiled GEMM (small M), dual-set via blockIdx.z ========
template<bool BT>
__global__ __launch_bounds__(256) void gemm_kernel(
    const float* __restrict__ A, const float* __restrict__ B,
    const float* __restrict__ bias, const float* __restrict__ rowscale,
    float* __restrict__ C,
    int M, int N, int K, int lda, int ldb, int ldc, int coff, int act,
    const float* __restrict__ A1, const float* __restrict__ B1,
    const float* __restrict__ bias1, float* __restrict__ C1, int coff1)
{
    if (blockIdx.z) { A = A1; B = B1; bias = bias1; C = C1; coff = coff1; }
    __shared__ float As[32][64 + 4];
    __shared__ float Bs[32][64 + 4];
    const int tid = threadIdx.x;
    const int m0 = blockIdx.y * 64;
    const int n0 = blockIdx.x * 64;
    const int ty = tid >> 4, tx = tid & 15;
    float acc[4][4] = {};
    for (int k0 = 0; k0 < K; k0 += 32) {
        #pragma unroll
        for (int r = 0; r < 2; ++r) {
            int f4 = tid + r * 256;
            int arw = f4 >> 3, af = (f4 & 7) << 2;
            float4 v = make_float4(0.f, 0.f, 0.f, 0.f);
            int grow = m0 + arw;
            if (grow < M) {
                v = *(const float4*)(A + (size_t)grow * lda + k0 + af);
                if (rowscale) { float s = rowscale[grow]; v.x *= s; v.y *= s; v.z *= s; v.w *= s; }
            }
            As[af + 0][arw] = v.x; As[af + 1][arw] = v.y; As[af + 2][arw] = v.z; As[af + 3][arw] = v.w;
        }
        #pragma unroll
        for (int r = 0; r < 2; ++r) {
            int f4 = tid + r * 256;
            int col = f4 >> 3, kf = (f4 & 7) << 2;
            float4 v = make_float4(0.f, 0.f, 0.f, 0.f);
            if (n0 + col < N) v = *(const float4*)(B + (size_t)(n0 + col) * ldb + k0 + kf);
            Bs[kf + 0][col] = v.x; Bs[kf + 1][col] = v.y; Bs[kf + 2][col] = v.z; Bs[kf + 3][col] = v.w;
        }
        __syncthreads();
        #pragma unroll
        for (int kk = 0; kk < 32; ++kk) {
            float4 a4 = *(const float4*)&As[kk][ty << 2];
            float4 b4 = *(const float4*)&Bs[kk][tx << 2];
            float a[4] = {a4.x, a4.y, a4.z, a4.w};
            float b[4] = {b4.x, b4.y, b4.z, b4.w};
            #pragma unroll
            for (int i = 0; i < 4; ++i)
                #pragma unroll
                for (int j = 0; j < 4; ++j)
                    acc[i][j] = fmaf(a[i], b[j], acc[i][j]);
        }
        __syncthreads();
    }
    #pragma unroll
    for (int i = 0; i < 4; ++i) {
        int row = m0 + (ty << 2) + i;
        if (row >= M) continue;
        #pragma unroll
        for (int j = 0; j < 4; ++j) {
            int col = n0 + (tx << 2) + j;
            if (col >= N) continue;
            float v = acc[i][j];
            if (bias) v += bias[col];
            if (act == 1) v = fmaxf(v, 0.f);
            else if (act == 2) v = (v > 0.f) ? v : expm1f(v);
            C[(size_t)row * ldc + coff + col] = v;
        }
    }
}

// ================= merged converts (one dispatch, 1280 blocks) ===============
__global__ __launch_bounds__(256) void conv_all_kernel(
    const float* __restrict__ fc_w0, const float* __restrict__ fc_w1,
    const float* __restrict__ gcn_w, const float* __restrict__ gt_wr,
    const float* __restrict__ gt_wf,
    u16* __restrict__ fcw_b, u16* __restrict__ gcnw_b,
    u16* __restrict__ wrN, u16* __restrict__ wfN)
{
    int bid = blockIdx.x, tid = threadIdx.x;
    if (bid < 256) {
        const float* src = bid < 128 ? fc_w0 : fc_w1;
        u16* dst = fcw_b + (bid < 128 ? 0 : 131072);
        int i = ((bid & 127) * 256 + tid) * 4;
        float4 v = *(const float4*)(src + i);
        *(uint2*)(dst + i) = make_uint2(pk2(v.x, v.y), pk2(v.z, v.w));
    } else if (bid < 768) {
        int idx = (bid - 256) * 256 + tid;   // 0..131071
        int l = idx >> 16, rem = idx & 65535;
        int k = rem >> 8, n = rem & 255;
        gcnw_b[(size_t)l * 65536 + n * 256 + k] = f2b(gcn_w[(size_t)l * 65536 + k * 256 + n]);
    } else {
        // frag-major conversion for gt_wr (bid 768..1023) and gt_wf (1024..1279)
        const float* w = bid < 1024 ? gt_wr : gt_wf;
        u16* dst = bid < 1024 ? wrN : wfN;
        int idx = ((bid & 255)) * 256 + tid; // 0..65535
        int lane = idx & 63;
        int kc = (idx >> 6) & 7;
        int gn = (idx >> 9) & 15;
        int l = idx >> 13;
        int row = gn * 16 + (lane & 15);
        int k0 = kc * 32 + (lane >> 4) * 8;
        const float* src = w + ((size_t)l * 256 + row) * 256 + k0;
        float4 v0 = *(const float4*)src;
        float4 v1 = *(const float4*)(src + 4);
        uint4 pk;
        pk.x = pk2(v0.x, v0.y); pk.y = pk2(v0.z, v0.w);
        pk.z = pk2(v1.x, v1.y); pk.w = pk2(v1.z, v1.w);
        *(uint4*)(dst + (size_t)idx * 8) = pk;
    }
}

// ================= CSR build (4 edges/thread, pipelined atomics) =============
#define EDGE_CAP 128
__global__ __launch_bounds__(256) void bucket_fill_kernel(
    const int* __restrict__ src, const int* __restrict__ dst,
    int* __restrict__ ebuf, int* __restrict__ cursor, int* __restrict__ cnt_out, int ne)
{
    int e0 = (blockIdx.x * 256 + threadIdx.x) * 4;
    if (e0 >= ne) return;
    int4 s4 = *(const int4*)(src + e0);
    int4 d4 = *(const int4*)(dst + e0);
    atomicAdd(&cnt_out[s4.x], 1);
    atomicAdd(&cnt_out[s4.y], 1);
    atomicAdd(&cnt_out[s4.z], 1);
    atomicAdd(&cnt_out[s4.w], 1);
    int p0 = atomicAdd(&cursor[d4.x], 1);
    int p1 = atomicAdd(&cursor[d4.y], 1);
    int p2 = atomicAdd(&cursor[d4.z], 1);
    int p3 = atomicAdd(&cursor[d4.w], 1);
    if (p0 < EDGE_CAP) ebuf[(size_t)d4.x * EDGE_CAP + p0] = s4.x;
    if (p1 < EDGE_CAP) ebuf[(size_t)d4.y * EDGE_CAP + p1] = s4.y;
    if (p2 < EDGE_CAP) ebuf[(size_t)d4.z * EDGE_CAP + p2] = s4.z;
    if (p3 < EDGE_CAP) ebuf[(size_t)d4.w * EDGE_CAP + p3] = s4.w;
}
__global__ __launch_bounds__(256) void deg_fin_kernel(const int* __restrict__ cnt, float* __restrict__ dinv, int n) {
    int i = blockIdx.x * 256 + threadIdx.x;
    if (i < n) dinv[i] = rsqrtf(fmaxf((float)cnt[i], 1.0f));
}

// ================= CSR aggregate, skips dead outputs per layer ===============
template<bool WF, bool WB>
__global__ __launch_bounds__(256) void csr_agg_kernel(
    const u16* __restrict__ x, const int* __restrict__ ebuf,
    const int* __restrict__ deg, float* __restrict__ outf, u16* __restrict__ outb, int nnodes)
{
    int n = blockIdx.x * 4 + (threadIdx.x >> 6);
    if (n >= nnodes) return;
    int lane = threadIdx.x & 63;
    int d = deg[n];
    float dinv = rsqrtf(fmaxf((float)d, 1.0f));
    if (d > EDGE_CAP) d = EDGE_CAP;
    const int* eb = ebuf + (size_t)n * EDGE_CAP;
    const int co = lane << 2;
    float a0 = 0.f, a1 = 0.f, a2 = 0.f, a3 = 0.f;
    int k = 0;
    for (; k + 4 <= d; k += 4) {
        int4 s4 = *(const int4*)(eb + k);
        uint2 va = *(const uint2*)(x + (size_t)s4.x * 256 + co);
        uint2 vb = *(const uint2*)(x + (size_t)s4.y * 256 + co);
        uint2 vc = *(const uint2*)(x + (size_t)s4.z * 256 + co);
        uint2 vd = *(const uint2*)(x + (size_t)s4.w * 256 + co);
        a0 += b2f_lo(va.x) + b2f_lo(vb.x) + b2f_lo(vc.x) + b2f_lo(vd.x);
        a1 += b2f_hi(va.x) + b2f_hi(vb.x) + b2f_hi(vc.x) + b2f_hi(vd.x);
        a2 += b2f_lo(va.y) + b2f_lo(vb.y) + b2f_lo(vc.y) + b2f_lo(vd.y);
        a3 += b2f_hi(va.y) + b2f_hi(vb.y) + b2f_hi(vc.y) + b2f_hi(vd.y);
    }
    for (; k < d; ++k) {
        int s = eb[k];
        uint2 v = *(const uint2*)(x + (size_t)s * 256 + co);
        a0 += b2f_lo(v.x); a1 += b2f_hi(v.x);
        a2 += b2f_lo(v.y); a3 += b2f_hi(v.y);
    }
    a0 = fmaxf(a0 * dinv, 0.f); a1 = fmaxf(a1 * dinv, 0.f);
    a2 = fmaxf(a2 * dinv, 0.f); a3 = fmaxf(a3 * dinv, 0.f);
    if (WF) *(float4*)(outf + (size_t)n * 256 + co) = make_float4(a0, a1, a2, a3);
    if (WB) *(uint2*)(outb + (size_t)n * 256 + co) = make_uint2(pk2(a0, a1), pk2(a2, a3));
}

// ================= fused MLP tail: m2 = relu(m1@w2^T+b2); out = sigmoid(m2.w3+b3)
__global__ __launch_bounds__(256) void mlp_tail_kernel(
    const float* __restrict__ m1, const float* __restrict__ w2,
    const float* __restrict__ b2, const float* __restrict__ w3,
    const float* __restrict__ b3, float* __restrict__ out)
{
    __shared__ float rowS[4][256];
    const int w = threadIdx.x >> 6, lane = threadIdx.x & 63;
    const int row = blockIdx.x * 4 + w;
    *(float4*)&rowS[w][lane * 4] = *(const float4*)(m1 + (size_t)row * 256 + lane * 4);
    __syncthreads();
    const float* rp = rowS[w];
    float v0 = b2[lane], v1 = b2[64 + lane];
    const float* wa = w2 + (size_t)lane * 256;
    const float* wb = w2 + (size_t)(64 + lane) * 256;
    #pragma unroll 8
    for (int d = 0; d < 256; d += 4) {
        float4 rv = *(const float4*)(rp + d);
        float4 a = *(const float4*)(wa + d);
        float4 b = *(const float4*)(wb + d);
        v0 = fmaf(rv.x, a.x, v0); v0 = fmaf(rv.y, a.y, v0);
        v0 = fmaf(rv.z, a.z, v0); v0 = fmaf(rv.w, a.w, v0);
        v1 = fmaf(rv.x, b.x, v1); v1 = fmaf(rv.y, b.y, v1);
        v1 = fmaf(rv.z, b.z, v1); v1 = fmaf(rv.w, b.w, v1);
    }
    v0 = fmaxf(v0, 0.f); v1 = fmaxf(v1, 0.f);
    float s = v0 * w3[lane] + v1 * w3[64 + lane];
    s = wave_sum(s);
    if (lane == 0) out[row] = 1.f / (1.f + expf(-(s + b3[0])));
}

static inline int cdiv(int a, int b) { return (a + b - 1) / b; }

extern "C" void kernel_launch(void* const* d_in, const int* in_sizes, int n_in,
                              void* d_out, int out_size, void* d_ws, size_t ws_size,
                              hipStream_t stream)
{
    const float* feat0   = (const float*)d_in[0];
    const float* feat1   = (const float*)d_in[1];
    const float* fc_w0   = (const float*)d_in[2];
    const float* fc_b0   = (const float*)d_in[3];
    const float* fc_w1   = (const float*)d_in[4];
    const float* fc_b1   = (const float*)d_in[5];
    const float* gcn_w   = (const float*)d_in[6];
    const int*   edge_src= (const int*)d_in[7];
    const int*   edge_dst= (const int*)d_in[8];
    const int*   dg_seqs = (const int*)d_in[9];
    const int*   pt_seqs = (const int*)d_in[10];
    // 11 type_emb, 12 node_type: dead; 13 gt_wl, 15 gt_al: dead (softmax cancellation)
    const float* gt_wr   = (const float*)d_in[14];
    const float* gt_ar   = (const float*)d_in[16];
    const float* gt_wf   = (const float*)d_in[17];
    const float* ln_g    = (const float*)d_in[18];
    const float* ln_b    = (const float*)d_in[19];
    const float* proj_d_w= (const float*)d_in[20];
    const float* proj_d_b= (const float*)d_in[21];
    const float* proj_p_w= (const float*)d_in[22];
    const float* proj_p_b= (const float*)d_in[23];
    const float* ml_w1   = (const float*)d_in[24];
    const float* ml_b1   = (const float*)d_in[25];
    const float* ml_w2   = (const float*)d_in[26];
    const float* ml_b2   = (const float*)d_in[27];
    const float* ml_w3   = (const float*)d_in[28];
    const float* ml_b3   = (const float*)d_in[29];
    float* out = (float*)d_out;

    // ---- workspace layout (f32 units) ----
    float* base  = (float*)d_ws;
    float* gh    = base;                      // 10,240,000
    float* gcnR  = gh + 10240000;             // GCN-phase region (15,440,000)
    float* dego  = gcnR + 15440000;           // 40,000
    float* embT  = dego + 40000;              // 524,288 (both types)
    float* t1    = embT + 524288;             // 524,288 (both types)
    float* mx    = t1 + 524288;               // 524,288
    float* m1    = mx + 524288;               // 262,144
    float* m2    = m1 + 262144;               // 131,072 (unused, kept for layout)
    float* wreg  = m2 + 131072;               // converted weights

    u16* tmp_b   = (u16*)gcnR;                        // 10,240,000 bf16
    int* ebuf    = (int*)(gcnR + 5120000);            // 5,120,000 int
    int* cursor  = ebuf + (size_t)40000 * EDGE_CAP;   // 40,000
    int* cnt_out = cursor + 40000;                    // 40,000
    u16* gh_b    = (u16*)(gcnR + 10320000);           // 10,240,000 bf16

    u16* fcw_b   = (u16*)wreg;                // 262,144 u16
    u16* gcnw_b  = fcw_b + 262144;            // 131,072 u16
    u16* wrN     = gcnw_b + 131072;           // 524,288 u16 (8 layers x 65,536)
    u16* wfN     = wrN + 524288;              // 524,288 u16 (8 layers x 65,536)

    // ---- merged weight converts (single dispatch) ----
    conv_all_kernel<<<1280, 256, 0, stream>>>(
        fc_w0, fc_w1, gcn_w, gt_wr, gt_wf, fcw_b, gcnw_b, wrN, wfN);

    // ---- FC projections (merged dual GEMM via blockIdx.z) -> gh_b ----
    mfma_gemm_kernel<true><<<dim3(2, cdiv(20000, 64), 2), 256, 0, stream>>>(
        feat0, fcw_b, fc_b0, nullptr, gh_b, 20000, 256, 512,
        feat1, fcw_b + 131072, fc_b1, gh_b + (size_t)20000 * 256);

    // ---- CSR build (once) ----
    hipMemsetAsync(cursor, 0, 80000 * sizeof(int), stream);
    bucket_fill_kernel<<<625, 256, 0, stream>>>(edge_src, edge_dst, ebuf, cursor, cnt_out, 640000);
    deg_fin_kernel<<<cdiv(40000, 256), 256, 0, stream>>>(cnt_out, dego, 40000);

    // ---- 2x GCN (layer 0 writes bf16 only; layer 1 writes f32 only) ----
    mfma_gemm_kernel<false><<<dim3(2, cdiv(40000, 64), 1), 256, 0, stream>>>(
        gh_b, gcnw_b, nullptr, dego, tmp_b, 40000, 256, 256,
        gh_b, gcnw_b, nullptr, tmp_b);
    csr_agg_kernel<false, true><<<10000, 256, 0, stream>>>(tmp_b, ebuf, cursor, gh, gh_b, 40000);
    mfma_gemm_kernel<false><<<dim3(2, cdiv(40000, 64), 1), 256, 0, stream>>>(
        gh_b, gcnw_b + 65536, nullptr, dego, tmp_b, 40000, 256, 256,
        gh_b, gcnw_b, nullptr, tmp_b);
    csr_agg_kernel<true, false><<<10000, 256, 0, stream>>>(tmp_b, ebuf, cursor, gh, gh_b, 40000);

    // ---- mega-fused graph transformer, both types in one dispatch ----
    fused_transformer_kernel<<<2048, 512, 0, stream>>>(
        gh, dg_seqs, pt_seqs, wrN, wfN, gt_ar, ln_g, ln_b, embT);

    // ---- proj heads (both types per dispatch via blockIdx.z) ----
    gemm_kernel<true><<<dim3(4, 16, 2), 256, 0, stream>>>(
        embT, proj_d_w, proj_d_b, nullptr, t1, 1024, 256, 256, 256, 256, 256, 0, 2,
        embT + 262144, proj_p_w, proj_p_b, t1 + 262144, 0);
    gemm_kernel<true><<<dim3(4, 16, 2), 256, 0, stream>>>(
        t1, proj_d_w + 65536, proj_d_b + 256, nullptr, mx, 1024, 256, 256, 256, 256, 512, 0, 0,
        t1 + 262144, proj_p_w + 65536, proj_p_b + 256, mx, 256);

    // ---- predict MLP: first GEMM, then fused tail ----
    gemm_kernel<true><<<dim3(4, 16, 1), 256, 0, stream>>>(
        mx, ml_w1, ml_b1, nullptr, m1, 1024, 256, 512, 512, 512, 256, 0, 1,
        mx, ml_w1, ml_b1, m1, 0);
    mlp_tail_kernel<<<256, 256, 0, stream>>>(m1, ml_w2, ml_b2, ml_w3, ml_b3, out);
}